// Round 1
// baseline (384.447 us; speedup 1.0000x reference)
//
#include <hip/hip_runtime.h>
#include <cstdint>
#include <cstddef>

// Problem constants: B=16, N=1024, D=768, H=12, HS=64, L=2
// Pipeline:
//  pack W2t/Wft/C (bf16, B^T layouts) ; LN1 -> xn(bf16)
//  GEMM1: xn(16384x768) @ W2t -> Vt[h][b*64+k][n]  (bf16)
//  circGEMM (per head h): C_h(1024x1024) @ Vt_h^T -> y ; x2 = x + y (f32 in d_out, bf16 copy)
//  GEMM2: x2 @ Wf0t + bf0 -> g (f32) ; LN+swish -> z1 (bf16)
//  GEMM3: z1 @ Wf1t + bf1 -> g ; final: LN+swish + x2, log_cosh -> d_out
//
// ws layout (bytes):
//  [0, 25165824)           slotA  : xn_bf16 -> x2_bf16 -> z1_bf16
//  [25165824, 50331648)    Vt     : 12*1024*1024 bf16          } later reused
//  [50331648, 75497472)    Cbf    : 12*1024*1024 bf16          } as g (f32, 50MB)
//  [75497472, 76677120)    W2t    : 768*768 bf16
//  [76677120, 79036416)    Wft    : 2*768*768 bf16
// total 79,036,416 B

typedef __attribute__((ext_vector_type(8))) short bf16x8;
typedef __attribute__((ext_vector_type(4))) float f32x4;
typedef __attribute__((ext_vector_type(4))) unsigned short us4;

__device__ __forceinline__ unsigned short f2bf(float f) {
  unsigned int u = __builtin_bit_cast(unsigned int, f);
  u += 0x7FFFu + ((u >> 16) & 1u);   // round-to-nearest-even
  return (unsigned short)(u >> 16);
}

// ---------------- pack kernels ----------------
__global__ __launch_bounds__(256) void pack_w2t(const float* __restrict__ Wv,
                                                unsigned short* __restrict__ W2t) {
  int o = blockIdx.x * 256 + threadIdx.x;   // < 589824
  int np = o / 768, d = o - np * 768;
  int h = np >> 6, k = np & 63;
  W2t[o] = f2bf(Wv[h * 49152 + d * 64 + k]);   // Wv[h][d][k]
}

__global__ __launch_bounds__(256) void pack_wft(const float* __restrict__ Wf,
                                                unsigned short* __restrict__ Wft) {
  int o = blockIdx.x * 256 + threadIdx.x;   // < 1179648
  int l = o / 589824, rem = o - l * 589824;
  int np = rem / 768, d = rem - np * 768;
  Wft[o] = f2bf(Wf[l * 589824 + d * 768 + np]);  // Wf[l][d][np]
}

__global__ __launch_bounds__(256) void pack_c(const float* __restrict__ alpha,
                                              unsigned short* __restrict__ Cbf) {
  int o = blockIdx.x * 256 + threadIdx.x;   // < 12582912
  int h = o >> 20, i = (o >> 10) & 1023, j = o & 1023;
  Cbf[o] = f2bf(alpha[(h << 10) + ((i - j) & 1023)]);
}

// ---------------- row LN helpers (D=768, block=256, 3 elems/thread) -------
__device__ __forceinline__ void block_reduce2(float& s, float& s2) {
#pragma unroll
  for (int off = 32; off > 0; off >>= 1) {
    s += __shfl_down(s, off);
    s2 += __shfl_down(s2, off);
  }
  __shared__ float ls[8];
  int w = threadIdx.x >> 6;
  if ((threadIdx.x & 63) == 0) { ls[w] = s; ls[w + 4] = s2; }
  __syncthreads();
  s = ls[0] + ls[1] + ls[2] + ls[3];
  s2 = ls[4] + ls[5] + ls[6] + ls[7];
}

__global__ __launch_bounds__(256) void ln1_kernel(const float* __restrict__ x,
                                                  const float* __restrict__ sc,
                                                  const float* __restrict__ bi,
                                                  unsigned short* __restrict__ out) {
  size_t base = (size_t)blockIdx.x * 768;
  int t = threadIdx.x;
  float v[3];
#pragma unroll
  for (int j = 0; j < 3; ++j) v[j] = x[base + t + j * 256];
  float s = v[0] + v[1] + v[2];
  float s2 = v[0] * v[0] + v[1] * v[1] + v[2] * v[2];
  block_reduce2(s, s2);
  float mu = s * (1.0f / 768.0f);
  float var = s2 * (1.0f / 768.0f) - mu * mu;
  float r = rsqrtf(var + 1e-6f);
#pragma unroll
  for (int j = 0; j < 3; ++j) {
    int d = t + j * 256;
    out[base + d] = f2bf((v[j] - mu) * r * sc[d] + bi[d]);
  }
}

__global__ __launch_bounds__(256) void lnswish_kernel(const float* __restrict__ g,
                                                      const float* __restrict__ sc,
                                                      const float* __restrict__ bi,
                                                      unsigned short* __restrict__ out) {
  size_t base = (size_t)blockIdx.x * 768;
  int t = threadIdx.x;
  float v[3];
#pragma unroll
  for (int j = 0; j < 3; ++j) v[j] = g[base + t + j * 256];
  float s = v[0] + v[1] + v[2];
  float s2 = v[0] * v[0] + v[1] * v[1] + v[2] * v[2];
  block_reduce2(s, s2);
  float mu = s * (1.0f / 768.0f);
  float var = s2 * (1.0f / 768.0f) - mu * mu;
  float r = rsqrtf(var + 1e-6f);
#pragma unroll
  for (int j = 0; j < 3; ++j) {
    int d = t + j * 256;
    float z = (v[j] - mu) * r * sc[d] + bi[d];
    float sw = z / (1.0f + expf(-z));
    out[base + d] = f2bf(sw);
  }
}

__global__ __launch_bounds__(256) void final_kernel(const float* __restrict__ g,
                                                    const float* __restrict__ sc,
                                                    const float* __restrict__ bi,
                                                    float* __restrict__ out) {
  size_t base = (size_t)blockIdx.x * 768;
  int t = threadIdx.x;
  float v[3];
#pragma unroll
  for (int j = 0; j < 3; ++j) v[j] = g[base + t + j * 256];
  float s = v[0] + v[1] + v[2];
  float s2 = v[0] * v[0] + v[1] * v[1] + v[2] * v[2];
  block_reduce2(s, s2);
  float mu = s * (1.0f / 768.0f);
  float var = s2 * (1.0f / 768.0f) - mu * mu;
  float r = rsqrtf(var + 1e-6f);
#pragma unroll
  for (int j = 0; j < 3; ++j) {
    int d = t + j * 256;
    float z = (v[j] - mu) * r * sc[d] + bi[d];
    float sw = z / (1.0f + expf(-z));
    float xx = sw + out[base + d];       // x2 was stored in d_out
    float ax = fabsf(xx);
    out[base + d] = ax + log1pf(expf(-2.0f * ax)) - 0.69314718055994531f;
  }
}

// ---------------- MFMA GEMM core: C(128x128) tile, BK=32, 4 waves --------
// A: MxK row-major bf16 ; Bt: NxK row-major bf16 (i.e. B transposed)
__device__ __forceinline__ void gemm_core(const unsigned short* __restrict__ A,
                                          const unsigned short* __restrict__ Bt,
                                          int K, int m0, int n0,
                                          unsigned short* sA, unsigned short* sB,
                                          f32x4 acc[4][4]) {
  const int tid = threadIdx.x;
  const int wave = tid >> 6, lane = tid & 63;
  const int wm = (wave >> 1) << 6, wn = (wave & 1) << 6;
  const int fm = lane & 15, fq = lane >> 4;
  const int srow = tid >> 2;        // 0..63
  const int sc8 = (tid & 3) << 3;   // 0,8,16,24

  for (int k0 = 0; k0 < K; k0 += 32) {
#pragma unroll
    for (int i = 0; i < 2; ++i) {
      int row = srow + i * 64;      // 0..127
      *(int4*)(sA + row * 32 + sc8) =
          *(const int4*)(A + (size_t)(m0 + row) * K + k0 + sc8);
      *(int4*)(sB + row * 32 + sc8) =
          *(const int4*)(Bt + (size_t)(n0 + row) * K + k0 + sc8);
    }
    __syncthreads();
    bf16x8 aq[4], bq[4];
#pragma unroll
    for (int t = 0; t < 4; ++t) {
      aq[t] = *(const bf16x8*)(sA + ((wm + (t << 4) + fm) << 5) + (fq << 3));
      bq[t] = *(const bf16x8*)(sB + ((wn + (t << 4) + fm) << 5) + (fq << 3));
    }
#pragma unroll
    for (int mt = 0; mt < 4; ++mt)
#pragma unroll
      for (int nt = 0; nt < 4; ++nt)
        acc[mt][nt] = __builtin_amdgcn_mfma_f32_16x16x32_bf16(aq[mt], bq[nt],
                                                              acc[mt][nt], 0, 0, 0);
    __syncthreads();
  }
}

// GEMM1: xn @ W2t -> Vt[h][b*64+k][n] (bf16)
__global__ __launch_bounds__(256) void gemm1_kernel(const unsigned short* __restrict__ A,
                                                    const unsigned short* __restrict__ Bt,
                                                    unsigned short* __restrict__ Vt) {
  __shared__ unsigned short sA[128 * 32];
  __shared__ unsigned short sB[128 * 32];
  f32x4 acc[4][4] = {};
  int m0 = blockIdx.y * 128, n0 = blockIdx.x * 128;
  gemm_core(A, Bt, 768, m0, n0, sA, sB, acc);
  const int wave = threadIdx.x >> 6, lane = threadIdx.x & 63;
  const int wm = (wave >> 1) << 6, wn = (wave & 1) << 6;
  const int fm = lane & 15, fq = lane >> 4;
#pragma unroll
  for (int mt = 0; mt < 4; ++mt) {
    int rowb = m0 + wm + (mt << 4) + (fq << 2);   // 4 consecutive rows
    int b = rowb >> 10, n = rowb & 1023;
#pragma unroll
    for (int nt = 0; nt < 4; ++nt) {
      int col = n0 + wn + (nt << 4) + fm;
      int h = col >> 6, ck = col & 63;
      size_t off = ((size_t)h << 20) + (size_t)((b << 6) + ck) * 1024 + n;
      us4 v;
#pragma unroll
      for (int r = 0; r < 4; ++r) v[r] = f2bf(acc[mt][nt][r]);
      *(us4*)(Vt + off) = v;
    }
  }
}

// circGEMM: per head, C_h @ V_h ; epilogue x2 = x + y
__global__ __launch_bounds__(256) void circ_kernel(const unsigned short* __restrict__ Cbf,
                                                   const unsigned short* __restrict__ Vt,
                                                   const float* __restrict__ xin,
                                                   float* __restrict__ x2f,
                                                   unsigned short* __restrict__ x2bf) {
  __shared__ unsigned short sA[128 * 32];
  __shared__ unsigned short sB[128 * 32];
  f32x4 acc[4][4] = {};
  int m0 = blockIdx.y * 128, n0 = blockIdx.x * 128;
  int h = blockIdx.z;
  gemm_core(Cbf + ((size_t)h << 20), Vt + ((size_t)h << 20), 1024, m0, n0, sA, sB, acc);
  const int wave = threadIdx.x >> 6, lane = threadIdx.x & 63;
  const int wm = (wave >> 1) << 6, wn = (wave & 1) << 6;
  const int fm = lane & 15, fq = lane >> 4;
#pragma unroll
  for (int mt = 0; mt < 4; ++mt) {
    int ib = m0 + wm + (mt << 4) + (fq << 2);
#pragma unroll
    for (int nt = 0; nt < 4; ++nt) {
      int c = n0 + wn + (nt << 4) + fm;
      int b = c >> 6, k = c & 63;
      size_t off = ((size_t)(b << 10) + ib) * 768 + (h << 6) + k;
#pragma unroll
      for (int r = 0; r < 4; ++r) {
        float val = acc[mt][nt][r] + xin[off + (size_t)r * 768];
        x2f[off + (size_t)r * 768] = val;
        x2bf[off + (size_t)r * 768] = f2bf(val);
      }
    }
  }
}

// FFN GEMM: A @ Wt + bias -> g (f32)
__global__ __launch_bounds__(256) void gemmf_kernel(const unsigned short* __restrict__ A,
                                                    const unsigned short* __restrict__ Bt,
                                                    const float* __restrict__ bias,
                                                    float* __restrict__ g) {
  __shared__ unsigned short sA[128 * 32];
  __shared__ unsigned short sB[128 * 32];
  f32x4 acc[4][4] = {};
  int m0 = blockIdx.y * 128, n0 = blockIdx.x * 128;
  gemm_core(A, Bt, 768, m0, n0, sA, sB, acc);
  const int wave = threadIdx.x >> 6, lane = threadIdx.x & 63;
  const int wm = (wave >> 1) << 6, wn = (wave & 1) << 6;
  const int fm = lane & 15, fq = lane >> 4;
#pragma unroll
  for (int mt = 0; mt < 4; ++mt) {
    int rowb = m0 + wm + (mt << 4) + (fq << 2);
#pragma unroll
    for (int nt = 0; nt < 4; ++nt) {
      int col = n0 + wn + (nt << 4) + fm;
      float bc = bias[col];
#pragma unroll
      for (int r = 0; r < 4; ++r)
        g[(size_t)(rowb + r) * 768 + col] = acc[mt][nt][r] + bc;
    }
  }
}

extern "C" void kernel_launch(void* const* d_in, const int* in_sizes, int n_in,
                              void* d_out, int out_size, void* d_ws, size_t ws_size,
                              hipStream_t stream) {
  const float* x = (const float*)d_in[0];
  const float* ln1_s = (const float*)d_in[1];
  const float* ln1_b = (const float*)d_in[2];
  const float* Wv = (const float*)d_in[3];
  const float* alpha = (const float*)d_in[4];
  const float* Wf = (const float*)d_in[5];
  const float* bf = (const float*)d_in[6];
  const float* lnf_s = (const float*)d_in[7];
  const float* lnf_b = (const float*)d_in[8];
  float* out = (float*)d_out;

  char* ws = (char*)d_ws;
  unsigned short* slotA = (unsigned short*)ws;                   // 25165824 B
  unsigned short* Vt = (unsigned short*)(ws + 25165824);         // 25165824 B
  unsigned short* Cbf = (unsigned short*)(ws + 50331648);        // 25165824 B
  float* g = (float*)(ws + 25165824);                            // 50331648 B (reuses Vt+Cbf)
  unsigned short* W2t = (unsigned short*)(ws + 75497472);        // 1179648 B
  unsigned short* Wft = (unsigned short*)(ws + 76677120);        // 2359296 B

  pack_w2t<<<2304, 256, 0, stream>>>(Wv, W2t);
  pack_wft<<<4608, 256, 0, stream>>>(Wf, Wft);
  pack_c<<<49152, 256, 0, stream>>>(alpha, Cbf);

  ln1_kernel<<<16384, 256, 0, stream>>>(x, ln1_s, ln1_b, slotA);
  gemm1_kernel<<<dim3(6, 128), 256, 0, stream>>>(slotA, W2t, Vt);
  circ_kernel<<<dim3(8, 8, 12), 256, 0, stream>>>(Cbf, Vt, x, out, slotA);
  gemmf_kernel<<<dim3(6, 128), 256, 0, stream>>>(slotA, Wft, bf, g);
  lnswish_kernel<<<16384, 256, 0, stream>>>(g, lnf_s, lnf_b, slotA);
  gemmf_kernel<<<dim3(6, 128), 256, 0, stream>>>(slotA, Wft + 589824, bf + 768, g);
  final_kernel<<<16384, 256, 0, stream>>>(g, lnf_s + 768, lnf_b + 768, out);
}

// Round 2
// 369.412 us; speedup vs baseline: 1.0407x; 1.0407x over previous
//
#include <hip/hip_runtime.h>
#include <cstdint>
#include <cstddef>

// Problem constants: B=16, N=1024, D=768, H=12, HS=64, L=2
// Pipeline:
//  pack W2t/Wft/C (bf16, B^T layouts) ; LN1 -> xn(bf16)
//  GEMM1: xn(16384x768) @ W2t -> Vt[h][b*64+k][n]  (bf16)
//  circGEMM (per head h): C_h(1024x1024) @ Vt_h^T -> y ; x2 = x + y (f32 in d_out, bf16 copy)
//  GEMM2: x2 @ Wf0t + bf0 -> g (f32) ; LN+swish -> z1 (bf16)
//  GEMM3: z1 @ Wf1t + bf1 -> g ; final: LN+swish + x2, log_cosh -> d_out
//
// R2 changes vs R1:
//  - gemm_core staging now uses __builtin_amdgcn_global_load_lds width=16
//    (m93->m97 ladder step; removes VGPR round-trip, overlaps loads w/ MFMA)
//  - LN/elementwise kernels: one wave per row, float4 loads, wave-only reduce
//
// ws layout (bytes):
//  [0, 25165824)           slotA  : xn_bf16 -> x2_bf16 -> z1_bf16
//  [25165824, 50331648)    Vt     : 12*1024*1024 bf16          } later reused
//  [50331648, 75497472)    Cbf    : 12*1024*1024 bf16          } as g (f32, 50MB)
//  [75497472, 76677120)    W2t    : 768*768 bf16
//  [76677120, 79036416)    Wft    : 2*768*768 bf16
// total 79,036,416 B

typedef __attribute__((ext_vector_type(8))) short bf16x8;
typedef __attribute__((ext_vector_type(4))) float f32x4;
typedef __attribute__((ext_vector_type(4))) unsigned short us4;

__device__ __forceinline__ unsigned short f2bf(float f) {
  unsigned int u = __builtin_bit_cast(unsigned int, f);
  u += 0x7FFFu + ((u >> 16) & 1u);   // round-to-nearest-even
  return (unsigned short)(u >> 16);
}

// async global->LDS, 16 bytes per lane; LDS dest must be wave-uniform base +
// lane*16 (our staging layout is exactly byte offset 16*tid per wave).
__device__ __forceinline__ void g2l16(const void* g, void* l) {
  __builtin_amdgcn_global_load_lds(
      (const __attribute__((address_space(1))) unsigned int*)g,
      (__attribute__((address_space(3))) unsigned int*)l,
      16, 0, 0);
}

// ---------------- pack kernels ----------------
__global__ __launch_bounds__(256) void pack_w2t(const float* __restrict__ Wv,
                                                unsigned short* __restrict__ W2t) {
  int o = blockIdx.x * 256 + threadIdx.x;   // < 589824
  int np = o / 768, d = o - np * 768;
  int h = np >> 6, k = np & 63;
  W2t[o] = f2bf(Wv[h * 49152 + d * 64 + k]);   // Wv[h][d][k]
}

__global__ __launch_bounds__(256) void pack_wft(const float* __restrict__ Wf,
                                                unsigned short* __restrict__ Wft) {
  int o = blockIdx.x * 256 + threadIdx.x;   // < 1179648
  int l = o / 589824, rem = o - l * 589824;
  int np = rem / 768, d = rem - np * 768;
  Wft[o] = f2bf(Wf[l * 589824 + d * 768 + np]);  // Wf[l][d][np]
}

__global__ __launch_bounds__(256) void pack_c(const float* __restrict__ alpha,
                                              unsigned short* __restrict__ Cbf) {
  int o = blockIdx.x * 256 + threadIdx.x;   // < 12582912
  int h = o >> 20, i = (o >> 10) & 1023, j = o & 1023;
  Cbf[o] = f2bf(alpha[(h << 10) + ((i - j) & 1023)]);
}

// ---------------- row kernels: 1 wave per row (D=768 = 64 lanes x 3 float4)
__device__ __forceinline__ void wave_reduce2(float& s, float& s2) {
#pragma unroll
  for (int off = 32; off > 0; off >>= 1) {
    s += __shfl_down(s, off);
    s2 += __shfl_down(s2, off);
  }
  s = __shfl(s, 0);
  s2 = __shfl(s2, 0);
}

__global__ __launch_bounds__(256) void ln1_kernel(const float* __restrict__ x,
                                                  const float* __restrict__ sc,
                                                  const float* __restrict__ bi,
                                                  unsigned short* __restrict__ out) {
  int row = blockIdx.x * 4 + (threadIdx.x >> 6);
  int lane = threadIdx.x & 63;
  size_t base = (size_t)row * 768;
  float4 v[3];
#pragma unroll
  for (int j = 0; j < 3; ++j) v[j] = *(const float4*)(x + base + lane * 4 + j * 256);
  float s = 0.f, s2 = 0.f;
#pragma unroll
  for (int j = 0; j < 3; ++j) {
    s += v[j].x + v[j].y + v[j].z + v[j].w;
    s2 += v[j].x * v[j].x + v[j].y * v[j].y + v[j].z * v[j].z + v[j].w * v[j].w;
  }
  wave_reduce2(s, s2);
  float mu = s * (1.0f / 768.0f);
  float var = s2 * (1.0f / 768.0f) - mu * mu;
  float r = rsqrtf(var + 1e-6f);
#pragma unroll
  for (int j = 0; j < 3; ++j) {
    int d = lane * 4 + j * 256;
    float4 scv = *(const float4*)(sc + d);
    float4 biv = *(const float4*)(bi + d);
    us4 o;
    o[0] = f2bf((v[j].x - mu) * r * scv.x + biv.x);
    o[1] = f2bf((v[j].y - mu) * r * scv.y + biv.y);
    o[2] = f2bf((v[j].z - mu) * r * scv.z + biv.z);
    o[3] = f2bf((v[j].w - mu) * r * scv.w + biv.w);
    *(us4*)(out + base + d) = o;
  }
}

__global__ __launch_bounds__(256) void lnswish_kernel(const float* __restrict__ g,
                                                      const float* __restrict__ sc,
                                                      const float* __restrict__ bi,
                                                      unsigned short* __restrict__ out) {
  int row = blockIdx.x * 4 + (threadIdx.x >> 6);
  int lane = threadIdx.x & 63;
  size_t base = (size_t)row * 768;
  float4 v[3];
#pragma unroll
  for (int j = 0; j < 3; ++j) v[j] = *(const float4*)(g + base + lane * 4 + j * 256);
  float s = 0.f, s2 = 0.f;
#pragma unroll
  for (int j = 0; j < 3; ++j) {
    s += v[j].x + v[j].y + v[j].z + v[j].w;
    s2 += v[j].x * v[j].x + v[j].y * v[j].y + v[j].z * v[j].z + v[j].w * v[j].w;
  }
  wave_reduce2(s, s2);
  float mu = s * (1.0f / 768.0f);
  float var = s2 * (1.0f / 768.0f) - mu * mu;
  float r = rsqrtf(var + 1e-6f);
#pragma unroll
  for (int j = 0; j < 3; ++j) {
    int d = lane * 4 + j * 256;
    float4 scv = *(const float4*)(sc + d);
    float4 biv = *(const float4*)(bi + d);
    float zz[4] = {(v[j].x - mu) * r * scv.x + biv.x, (v[j].y - mu) * r * scv.y + biv.y,
                   (v[j].z - mu) * r * scv.z + biv.z, (v[j].w - mu) * r * scv.w + biv.w};
    us4 o;
#pragma unroll
    for (int q = 0; q < 4; ++q) o[q] = f2bf(zz[q] / (1.0f + expf(-zz[q])));
    *(us4*)(out + base + d) = o;
  }
}

__global__ __launch_bounds__(256) void final_kernel(const float* __restrict__ g,
                                                    const float* __restrict__ sc,
                                                    const float* __restrict__ bi,
                                                    float* __restrict__ out) {
  int row = blockIdx.x * 4 + (threadIdx.x >> 6);
  int lane = threadIdx.x & 63;
  size_t base = (size_t)row * 768;
  float4 v[3];
#pragma unroll
  for (int j = 0; j < 3; ++j) v[j] = *(const float4*)(g + base + lane * 4 + j * 256);
  float s = 0.f, s2 = 0.f;
#pragma unroll
  for (int j = 0; j < 3; ++j) {
    s += v[j].x + v[j].y + v[j].z + v[j].w;
    s2 += v[j].x * v[j].x + v[j].y * v[j].y + v[j].z * v[j].z + v[j].w * v[j].w;
  }
  wave_reduce2(s, s2);
  float mu = s * (1.0f / 768.0f);
  float var = s2 * (1.0f / 768.0f) - mu * mu;
  float r = rsqrtf(var + 1e-6f);
#pragma unroll
  for (int j = 0; j < 3; ++j) {
    int d = lane * 4 + j * 256;
    float4 scv = *(const float4*)(sc + d);
    float4 biv = *(const float4*)(bi + d);
    float4 xv = *(const float4*)(out + base + d);   // x2 stored in d_out
    float zz[4] = {(v[j].x - mu) * r * scv.x + biv.x, (v[j].y - mu) * r * scv.y + biv.y,
                   (v[j].z - mu) * r * scv.z + biv.z, (v[j].w - mu) * r * scv.w + biv.w};
    float xx[4] = {xv.x, xv.y, xv.z, xv.w};
    float4 o;
    float* op = &o.x;
#pragma unroll
    for (int q = 0; q < 4; ++q) {
      float sw = zz[q] / (1.0f + expf(-zz[q]));
      float t = sw + xx[q];
      float ax = fabsf(t);
      op[q] = ax + log1pf(expf(-2.0f * ax)) - 0.69314718055994531f;
    }
    *(float4*)(out + base + d) = o;
  }
}

// ---------------- MFMA GEMM core: C(128x128) tile, BK=32, 4 waves --------
// A: MxK row-major bf16 ; Bt: NxK row-major bf16 (i.e. B transposed)
// Staging via global_load_lds width=16: LDS byte offset = 16*tid per wave,
// i.e. wave-uniform base + lane*16 (required layout).
__device__ __forceinline__ void gemm_core(const unsigned short* __restrict__ A,
                                          const unsigned short* __restrict__ Bt,
                                          int K, int m0, int n0,
                                          unsigned short* sA, unsigned short* sB,
                                          f32x4 acc[4][4]) {
  const int tid = threadIdx.x;
  const int wave = tid >> 6, lane = tid & 63;
  const int wm = (wave >> 1) << 6, wn = (wave & 1) << 6;
  const int fm = lane & 15, fq = lane >> 4;
  const int srow = tid >> 2;        // 0..63
  const int sc8 = (tid & 3) << 3;   // 0,8,16,24

  for (int k0 = 0; k0 < K; k0 += 32) {
#pragma unroll
    for (int i = 0; i < 2; ++i) {
      int row = srow + i * 64;      // 0..127
      g2l16(A + (size_t)(m0 + row) * K + k0 + sc8, sA + row * 32 + sc8);
      g2l16(Bt + (size_t)(n0 + row) * K + k0 + sc8, sB + row * 32 + sc8);
    }
    __syncthreads();
    bf16x8 aq[4], bq[4];
#pragma unroll
    for (int t = 0; t < 4; ++t) {
      aq[t] = *(const bf16x8*)(sA + ((wm + (t << 4) + fm) << 5) + (fq << 3));
      bq[t] = *(const bf16x8*)(sB + ((wn + (t << 4) + fm) << 5) + (fq << 3));
    }
#pragma unroll
    for (int mt = 0; mt < 4; ++mt)
#pragma unroll
      for (int nt = 0; nt < 4; ++nt)
        acc[mt][nt] = __builtin_amdgcn_mfma_f32_16x16x32_bf16(aq[mt], bq[nt],
                                                              acc[mt][nt], 0, 0, 0);
    __syncthreads();
  }
}

// GEMM1: xn @ W2t -> Vt[h][b*64+k][n] (bf16)
__global__ __launch_bounds__(256) void gemm1_kernel(const unsigned short* __restrict__ A,
                                                    const unsigned short* __restrict__ Bt,
                                                    unsigned short* __restrict__ Vt) {
  __shared__ unsigned short sA[128 * 32];
  __shared__ unsigned short sB[128 * 32];
  f32x4 acc[4][4] = {};
  int m0 = blockIdx.y * 128, n0 = blockIdx.x * 128;
  gemm_core(A, Bt, 768, m0, n0, sA, sB, acc);
  const int wave = threadIdx.x >> 6, lane = threadIdx.x & 63;
  const int wm = (wave >> 1) << 6, wn = (wave & 1) << 6;
  const int fm = lane & 15, fq = lane >> 4;
#pragma unroll
  for (int mt = 0; mt < 4; ++mt) {
    int rowb = m0 + wm + (mt << 4) + (fq << 2);   // 4 consecutive rows
    int b = rowb >> 10, n = rowb & 1023;
#pragma unroll
    for (int nt = 0; nt < 4; ++nt) {
      int col = n0 + wn + (nt << 4) + fm;
      int h = col >> 6, ck = col & 63;
      size_t off = ((size_t)h << 20) + (size_t)((b << 6) + ck) * 1024 + n;
      us4 v;
#pragma unroll
      for (int r = 0; r < 4; ++r) v[r] = f2bf(acc[mt][nt][r]);
      *(us4*)(Vt + off) = v;
    }
  }
}

// circGEMM: per head, C_h @ V_h ; epilogue x2 = x + y
__global__ __launch_bounds__(256) void circ_kernel(const unsigned short* __restrict__ Cbf,
                                                   const unsigned short* __restrict__ Vt,
                                                   const float* __restrict__ xin,
                                                   float* __restrict__ x2f,
                                                   unsigned short* __restrict__ x2bf) {
  __shared__ unsigned short sA[128 * 32];
  __shared__ unsigned short sB[128 * 32];
  f32x4 acc[4][4] = {};
  int m0 = blockIdx.y * 128, n0 = blockIdx.x * 128;
  int h = blockIdx.z;
  gemm_core(Cbf + ((size_t)h << 20), Vt + ((size_t)h << 20), 1024, m0, n0, sA, sB, acc);
  const int wave = threadIdx.x >> 6, lane = threadIdx.x & 63;
  const int wm = (wave >> 1) << 6, wn = (wave & 1) << 6;
  const int fm = lane & 15, fq = lane >> 4;
#pragma unroll
  for (int mt = 0; mt < 4; ++mt) {
    int ib = m0 + wm + (mt << 4) + (fq << 2);
#pragma unroll
    for (int nt = 0; nt < 4; ++nt) {
      int c = n0 + wn + (nt << 4) + fm;
      int b = c >> 6, k = c & 63;
      size_t off = ((size_t)(b << 10) + ib) * 768 + (h << 6) + k;
#pragma unroll
      for (int r = 0; r < 4; ++r) {
        float val = acc[mt][nt][r] + xin[off + (size_t)r * 768];
        x2f[off + (size_t)r * 768] = val;
        x2bf[off + (size_t)r * 768] = f2bf(val);
      }
    }
  }
}

// FFN GEMM: A @ Wt + bias -> g (f32)
__global__ __launch_bounds__(256) void gemmf_kernel(const unsigned short* __restrict__ A,
                                                    const unsigned short* __restrict__ Bt,
                                                    const float* __restrict__ bias,
                                                    float* __restrict__ g) {
  __shared__ unsigned short sA[128 * 32];
  __shared__ unsigned short sB[128 * 32];
  f32x4 acc[4][4] = {};
  int m0 = blockIdx.y * 128, n0 = blockIdx.x * 128;
  gemm_core(A, Bt, 768, m0, n0, sA, sB, acc);
  const int wave = threadIdx.x >> 6, lane = threadIdx.x & 63;
  const int wm = (wave >> 1) << 6, wn = (wave & 1) << 6;
  const int fm = lane & 15, fq = lane >> 4;
#pragma unroll
  for (int mt = 0; mt < 4; ++mt) {
    int rowb = m0 + wm + (mt << 4) + (fq << 2);
#pragma unroll
    for (int nt = 0; nt < 4; ++nt) {
      int col = n0 + wn + (nt << 4) + fm;
      float bc = bias[col];
#pragma unroll
      for (int r = 0; r < 4; ++r)
        g[(size_t)(rowb + r) * 768 + col] = acc[mt][nt][r] + bc;
    }
  }
}

extern "C" void kernel_launch(void* const* d_in, const int* in_sizes, int n_in,
                              void* d_out, int out_size, void* d_ws, size_t ws_size,
                              hipStream_t stream) {
  const float* x = (const float*)d_in[0];
  const float* ln1_s = (const float*)d_in[1];
  const float* ln1_b = (const float*)d_in[2];
  const float* Wv = (const float*)d_in[3];
  const float* alpha = (const float*)d_in[4];
  const float* Wf = (const float*)d_in[5];
  const float* bf = (const float*)d_in[6];
  const float* lnf_s = (const float*)d_in[7];
  const float* lnf_b = (const float*)d_in[8];
  float* out = (float*)d_out;

  char* ws = (char*)d_ws;
  unsigned short* slotA = (unsigned short*)ws;                   // 25165824 B
  unsigned short* Vt = (unsigned short*)(ws + 25165824);         // 25165824 B
  unsigned short* Cbf = (unsigned short*)(ws + 50331648);        // 25165824 B
  float* g = (float*)(ws + 25165824);                            // 50331648 B (reuses Vt+Cbf)
  unsigned short* W2t = (unsigned short*)(ws + 75497472);        // 1179648 B
  unsigned short* Wft = (unsigned short*)(ws + 76677120);        // 2359296 B

  pack_w2t<<<2304, 256, 0, stream>>>(Wv, W2t);
  pack_wft<<<4608, 256, 0, stream>>>(Wf, Wft);
  pack_c<<<49152, 256, 0, stream>>>(alpha, Cbf);

  ln1_kernel<<<4096, 256, 0, stream>>>(x, ln1_s, ln1_b, slotA);
  gemm1_kernel<<<dim3(6, 128), 256, 0, stream>>>(slotA, W2t, Vt);
  circ_kernel<<<dim3(8, 8, 12), 256, 0, stream>>>(Cbf, Vt, x, out, slotA);
  gemmf_kernel<<<dim3(6, 128), 256, 0, stream>>>(slotA, Wft, bf, g);
  lnswish_kernel<<<4096, 256, 0, stream>>>(g, lnf_s, lnf_b, slotA);
  gemmf_kernel<<<dim3(6, 128), 256, 0, stream>>>(slotA, Wft + 589824, bf + 768, g);
  final_kernel<<<4096, 256, 0, stream>>>(g, lnf_s + 768, lnf_b + 768, out);
}

// Round 3
// 355.165 us; speedup vs baseline: 1.0824x; 1.0401x over previous
//
#include <hip/hip_runtime.h>
#include <cstdint>
#include <cstddef>

// Problem constants: B=16, N=1024, D=768, H=12, HS=64, L=2
// Pipeline:
//  pack W2t/Wft/C (bf16, B^T layouts) ; LN1 -> xn(bf16)
//  GEMM1: xn(16384x768) @ W2t -> Vt[h][b*64+k][n]  (bf16)
//  circGEMM (per head h): C_h(1024x1024) @ Vt_h^T -> y ; x2 = x + y (f32 in d_out, bf16 copy)
//  GEMM2: x2 @ Wf0t + bf0 -> g (f32) ; LN+swish -> z1 (bf16)
//  GEMM3: z1 @ Wf1t + bf1 -> g ; final: LN+swish + x2, log_cosh -> d_out
//
// R3 change vs R2: XCD-aware block swizzle on all GEMMs.
//  XCD assignment heuristic: xcd = flat_block_id % 8 (round-robin dispatch).
//  circ: each XCD gets a 2x4 tile region per head -> per-XCD/head working set
//        (2+4)*256KB = 1.5MB, L2-resident (was: all m-strips of all heads,
//        24MB through 4MB L2 -> L3 thrash).
//  gemm1/gemmf: each XCD owns m-strips {xcd, xcd+8, ...} -> A 3MB + B 1.2MB
//        per XCD, L2-resident.
//
// ws layout (bytes):
//  [0, 25165824)           slotA  : xn_bf16 -> x2_bf16 -> z1_bf16
//  [25165824, 50331648)    Vt     : 12*1024*1024 bf16          } later reused
//  [50331648, 75497472)    Cbf    : 12*1024*1024 bf16          } as g (f32, 50MB)
//  [75497472, 76677120)    W2t    : 768*768 bf16
//  [76677120, 79036416)    Wft    : 2*768*768 bf16
// total 79,036,416 B

typedef __attribute__((ext_vector_type(8))) short bf16x8;
typedef __attribute__((ext_vector_type(4))) float f32x4;
typedef __attribute__((ext_vector_type(4))) unsigned short us4;

__device__ __forceinline__ unsigned short f2bf(float f) {
  unsigned int u = __builtin_bit_cast(unsigned int, f);
  u += 0x7FFFu + ((u >> 16) & 1u);   // round-to-nearest-even
  return (unsigned short)(u >> 16);
}

// async global->LDS, 16 bytes per lane; LDS dest must be wave-uniform base +
// lane*16 (our staging layout is exactly byte offset 16*tid per wave).
__device__ __forceinline__ void g2l16(const void* g, void* l) {
  __builtin_amdgcn_global_load_lds(
      (const __attribute__((address_space(1))) unsigned int*)g,
      (__attribute__((address_space(3))) unsigned int*)l,
      16, 0, 0);
}

// ---------------- pack kernels ----------------
__global__ __launch_bounds__(256) void pack_w2t(const float* __restrict__ Wv,
                                                unsigned short* __restrict__ W2t) {
  int o = blockIdx.x * 256 + threadIdx.x;   // < 589824
  int np = o / 768, d = o - np * 768;
  int h = np >> 6, k = np & 63;
  W2t[o] = f2bf(Wv[h * 49152 + d * 64 + k]);   // Wv[h][d][k]
}

__global__ __launch_bounds__(256) void pack_wft(const float* __restrict__ Wf,
                                                unsigned short* __restrict__ Wft) {
  int o = blockIdx.x * 256 + threadIdx.x;   // < 1179648
  int l = o / 589824, rem = o - l * 589824;
  int np = rem / 768, d = rem - np * 768;
  Wft[o] = f2bf(Wf[l * 589824 + d * 768 + np]);  // Wf[l][d][np]
}

__global__ __launch_bounds__(256) void pack_c(const float* __restrict__ alpha,
                                              unsigned short* __restrict__ Cbf) {
  int o = blockIdx.x * 256 + threadIdx.x;   // < 12582912
  int h = o >> 20, i = (o >> 10) & 1023, j = o & 1023;
  Cbf[o] = f2bf(alpha[(h << 10) + ((i - j) & 1023)]);
}

// ---------------- row kernels: 1 wave per row (D=768 = 64 lanes x 3 float4)
__device__ __forceinline__ void wave_reduce2(float& s, float& s2) {
#pragma unroll
  for (int off = 32; off > 0; off >>= 1) {
    s += __shfl_down(s, off);
    s2 += __shfl_down(s2, off);
  }
  s = __shfl(s, 0);
  s2 = __shfl(s2, 0);
}

__global__ __launch_bounds__(256) void ln1_kernel(const float* __restrict__ x,
                                                  const float* __restrict__ sc,
                                                  const float* __restrict__ bi,
                                                  unsigned short* __restrict__ out) {
  int row = blockIdx.x * 4 + (threadIdx.x >> 6);
  int lane = threadIdx.x & 63;
  size_t base = (size_t)row * 768;
  float4 v[3];
#pragma unroll
  for (int j = 0; j < 3; ++j) v[j] = *(const float4*)(x + base + lane * 4 + j * 256);
  float s = 0.f, s2 = 0.f;
#pragma unroll
  for (int j = 0; j < 3; ++j) {
    s += v[j].x + v[j].y + v[j].z + v[j].w;
    s2 += v[j].x * v[j].x + v[j].y * v[j].y + v[j].z * v[j].z + v[j].w * v[j].w;
  }
  wave_reduce2(s, s2);
  float mu = s * (1.0f / 768.0f);
  float var = s2 * (1.0f / 768.0f) - mu * mu;
  float r = rsqrtf(var + 1e-6f);
#pragma unroll
  for (int j = 0; j < 3; ++j) {
    int d = lane * 4 + j * 256;
    float4 scv = *(const float4*)(sc + d);
    float4 biv = *(const float4*)(bi + d);
    us4 o;
    o[0] = f2bf((v[j].x - mu) * r * scv.x + biv.x);
    o[1] = f2bf((v[j].y - mu) * r * scv.y + biv.y);
    o[2] = f2bf((v[j].z - mu) * r * scv.z + biv.z);
    o[3] = f2bf((v[j].w - mu) * r * scv.w + biv.w);
    *(us4*)(out + base + d) = o;
  }
}

__global__ __launch_bounds__(256) void lnswish_kernel(const float* __restrict__ g,
                                                      const float* __restrict__ sc,
                                                      const float* __restrict__ bi,
                                                      unsigned short* __restrict__ out) {
  int row = blockIdx.x * 4 + (threadIdx.x >> 6);
  int lane = threadIdx.x & 63;
  size_t base = (size_t)row * 768;
  float4 v[3];
#pragma unroll
  for (int j = 0; j < 3; ++j) v[j] = *(const float4*)(g + base + lane * 4 + j * 256);
  float s = 0.f, s2 = 0.f;
#pragma unroll
  for (int j = 0; j < 3; ++j) {
    s += v[j].x + v[j].y + v[j].z + v[j].w;
    s2 += v[j].x * v[j].x + v[j].y * v[j].y + v[j].z * v[j].z + v[j].w * v[j].w;
  }
  wave_reduce2(s, s2);
  float mu = s * (1.0f / 768.0f);
  float var = s2 * (1.0f / 768.0f) - mu * mu;
  float r = rsqrtf(var + 1e-6f);
#pragma unroll
  for (int j = 0; j < 3; ++j) {
    int d = lane * 4 + j * 256;
    float4 scv = *(const float4*)(sc + d);
    float4 biv = *(const float4*)(bi + d);
    float zz[4] = {(v[j].x - mu) * r * scv.x + biv.x, (v[j].y - mu) * r * scv.y + biv.y,
                   (v[j].z - mu) * r * scv.z + biv.z, (v[j].w - mu) * r * scv.w + biv.w};
    us4 o;
#pragma unroll
    for (int q = 0; q < 4; ++q) o[q] = f2bf(zz[q] / (1.0f + expf(-zz[q])));
    *(us4*)(out + base + d) = o;
  }
}

__global__ __launch_bounds__(256) void final_kernel(const float* __restrict__ g,
                                                    const float* __restrict__ sc,
                                                    const float* __restrict__ bi,
                                                    float* __restrict__ out) {
  int row = blockIdx.x * 4 + (threadIdx.x >> 6);
  int lane = threadIdx.x & 63;
  size_t base = (size_t)row * 768;
  float4 v[3];
#pragma unroll
  for (int j = 0; j < 3; ++j) v[j] = *(const float4*)(g + base + lane * 4 + j * 256);
  float s = 0.f, s2 = 0.f;
#pragma unroll
  for (int j = 0; j < 3; ++j) {
    s += v[j].x + v[j].y + v[j].z + v[j].w;
    s2 += v[j].x * v[j].x + v[j].y * v[j].y + v[j].z * v[j].z + v[j].w * v[j].w;
  }
  wave_reduce2(s, s2);
  float mu = s * (1.0f / 768.0f);
  float var = s2 * (1.0f / 768.0f) - mu * mu;
  float r = rsqrtf(var + 1e-6f);
#pragma unroll
  for (int j = 0; j < 3; ++j) {
    int d = lane * 4 + j * 256;
    float4 scv = *(const float4*)(sc + d);
    float4 biv = *(const float4*)(bi + d);
    float4 xv = *(const float4*)(out + base + d);   // x2 stored in d_out
    float zz[4] = {(v[j].x - mu) * r * scv.x + biv.x, (v[j].y - mu) * r * scv.y + biv.y,
                   (v[j].z - mu) * r * scv.z + biv.z, (v[j].w - mu) * r * scv.w + biv.w};
    float xx[4] = {xv.x, xv.y, xv.z, xv.w};
    float4 o;
    float* op = &o.x;
#pragma unroll
    for (int q = 0; q < 4; ++q) {
      float sw = zz[q] / (1.0f + expf(-zz[q]));
      float t = sw + xx[q];
      float ax = fabsf(t);
      op[q] = ax + log1pf(expf(-2.0f * ax)) - 0.69314718055994531f;
    }
    *(float4*)(out + base + d) = o;
  }
}

// ---------------- MFMA GEMM core: C(128x128) tile, BK=32, 4 waves --------
// A: MxK row-major bf16 ; Bt: NxK row-major bf16 (i.e. B transposed)
// Staging via global_load_lds width=16: LDS byte offset = 16*tid per wave.
__device__ __forceinline__ void gemm_core(const unsigned short* __restrict__ A,
                                          const unsigned short* __restrict__ Bt,
                                          int K, int m0, int n0,
                                          unsigned short* sA, unsigned short* sB,
                                          f32x4 acc[4][4]) {
  const int tid = threadIdx.x;
  const int wave = tid >> 6, lane = tid & 63;
  const int wm = (wave >> 1) << 6, wn = (wave & 1) << 6;
  const int fm = lane & 15, fq = lane >> 4;
  const int srow = tid >> 2;        // 0..63
  const int sc8 = (tid & 3) << 3;   // 0,8,16,24

  for (int k0 = 0; k0 < K; k0 += 32) {
#pragma unroll
    for (int i = 0; i < 2; ++i) {
      int row = srow + i * 64;      // 0..127
      g2l16(A + (size_t)(m0 + row) * K + k0 + sc8, sA + row * 32 + sc8);
      g2l16(Bt + (size_t)(n0 + row) * K + k0 + sc8, sB + row * 32 + sc8);
    }
    __syncthreads();
    bf16x8 aq[4], bq[4];
#pragma unroll
    for (int t = 0; t < 4; ++t) {
      aq[t] = *(const bf16x8*)(sA + ((wm + (t << 4) + fm) << 5) + (fq << 3));
      bq[t] = *(const bf16x8*)(sB + ((wn + (t << 4) + fm) << 5) + (fq << 3));
    }
#pragma unroll
    for (int mt = 0; mt < 4; ++mt)
#pragma unroll
      for (int nt = 0; nt < 4; ++nt)
        acc[mt][nt] = __builtin_amdgcn_mfma_f32_16x16x32_bf16(aq[mt], bq[nt],
                                                              acc[mt][nt], 0, 0, 0);
    __syncthreads();
  }
}

// XCD-swizzled decode for 16384x768-output GEMMs (128 m-tiles x 6 n-tiles).
// Each XCD (= flat%8) owns m-strips {xcd, xcd+8, ...}: A 3MB + B 1.2MB in L2.
__device__ __forceinline__ void decode_mn_768(int f, int& m0, int& n0) {
  int xcd = f & 7, s = f >> 3;        // s in [0,96)
  int g = s / 6, bx = s - g * 6;      // g in [0,16)
  m0 = (xcd + g * 8) << 7;
  n0 = bx << 7;
}

// GEMM1: xn @ W2t -> Vt[h][b*64+k][n] (bf16)
__global__ __launch_bounds__(256) void gemm1_kernel(const unsigned short* __restrict__ A,
                                                    const unsigned short* __restrict__ Bt,
                                                    unsigned short* __restrict__ Vt) {
  __shared__ unsigned short sA[128 * 32];
  __shared__ unsigned short sB[128 * 32];
  f32x4 acc[4][4] = {};
  int m0, n0;
  decode_mn_768(blockIdx.x, m0, n0);
  gemm_core(A, Bt, 768, m0, n0, sA, sB, acc);
  const int wave = threadIdx.x >> 6, lane = threadIdx.x & 63;
  const int wm = (wave >> 1) << 6, wn = (wave & 1) << 6;
  const int fm = lane & 15, fq = lane >> 4;
#pragma unroll
  for (int mt = 0; mt < 4; ++mt) {
    int rowb = m0 + wm + (mt << 4) + (fq << 2);   // 4 consecutive rows
    int b = rowb >> 10, n = rowb & 1023;
#pragma unroll
    for (int nt = 0; nt < 4; ++nt) {
      int col = n0 + wn + (nt << 4) + fm;
      int h = col >> 6, ck = col & 63;
      size_t off = ((size_t)h << 20) + (size_t)((b << 6) + ck) * 1024 + n;
      us4 v;
#pragma unroll
      for (int r = 0; r < 4; ++r) v[r] = f2bf(acc[mt][nt][r]);
      *(us4*)(Vt + off) = v;
    }
  }
}

// circGEMM: per head, C_h @ V_h ; epilogue x2 = x + y
// Swizzle: xcd = flat%8 gets a 2x4 (m x n) tile region per head ->
// per-XCD/head working set 1.5MB (L2-resident).
__global__ __launch_bounds__(256) void circ_kernel(const unsigned short* __restrict__ Cbf,
                                                   const unsigned short* __restrict__ Vt,
                                                   const float* __restrict__ xin,
                                                   float* __restrict__ x2f,
                                                   unsigned short* __restrict__ x2bf) {
  __shared__ unsigned short sA[128 * 32];
  __shared__ unsigned short sB[128 * 32];
  f32x4 acc[4][4] = {};
  int f = blockIdx.x;                 // [0,768)
  int xcd = f & 7, s = f >> 3;        // s in [0,96)
  int h = s >> 3, t = s & 7;          // 12 heads x 8 tiles-per-XCD-per-head
  int mr = xcd >> 1, nr = xcd & 1;    // region: 2 m-tiles x 4 n-tiles
  int m0 = ((mr << 1) + (t >> 2)) << 7;
  int n0 = ((nr << 2) + (t & 3)) << 7;
  gemm_core(Cbf + ((size_t)h << 20), Vt + ((size_t)h << 20), 1024, m0, n0, sA, sB, acc);
  const int wave = threadIdx.x >> 6, lane = threadIdx.x & 63;
  const int wm = (wave >> 1) << 6, wn = (wave & 1) << 6;
  const int fm = lane & 15, fq = lane >> 4;
#pragma unroll
  for (int mt = 0; mt < 4; ++mt) {
    int ib = m0 + wm + (mt << 4) + (fq << 2);
#pragma unroll
    for (int nt = 0; nt < 4; ++nt) {
      int c = n0 + wn + (nt << 4) + fm;
      int b = c >> 6, k = c & 63;
      size_t off = ((size_t)(b << 10) + ib) * 768 + (h << 6) + k;
#pragma unroll
      for (int r = 0; r < 4; ++r) {
        float val = acc[mt][nt][r] + xin[off + (size_t)r * 768];
        x2f[off + (size_t)r * 768] = val;
        x2bf[off + (size_t)r * 768] = f2bf(val);
      }
    }
  }
}

// FFN GEMM: A @ Wt + bias -> g (f32)
__global__ __launch_bounds__(256) void gemmf_kernel(const unsigned short* __restrict__ A,
                                                    const unsigned short* __restrict__ Bt,
                                                    const float* __restrict__ bias,
                                                    float* __restrict__ g) {
  __shared__ unsigned short sA[128 * 32];
  __shared__ unsigned short sB[128 * 32];
  f32x4 acc[4][4] = {};
  int m0, n0;
  decode_mn_768(blockIdx.x, m0, n0);
  gemm_core(A, Bt, 768, m0, n0, sA, sB, acc);
  const int wave = threadIdx.x >> 6, lane = threadIdx.x & 63;
  const int wm = (wave >> 1) << 6, wn = (wave & 1) << 6;
  const int fm = lane & 15, fq = lane >> 4;
#pragma unroll
  for (int mt = 0; mt < 4; ++mt) {
    int rowb = m0 + wm + (mt << 4) + (fq << 2);
#pragma unroll
    for (int nt = 0; nt < 4; ++nt) {
      int col = n0 + wn + (nt << 4) + fm;
      float bc = bias[col];
#pragma unroll
      for (int r = 0; r < 4; ++r)
        g[(size_t)(rowb + r) * 768 + col] = acc[mt][nt][r] + bc;
    }
  }
}

extern "C" void kernel_launch(void* const* d_in, const int* in_sizes, int n_in,
                              void* d_out, int out_size, void* d_ws, size_t ws_size,
                              hipStream_t stream) {
  const float* x = (const float*)d_in[0];
  const float* ln1_s = (const float*)d_in[1];
  const float* ln1_b = (const float*)d_in[2];
  const float* Wv = (const float*)d_in[3];
  const float* alpha = (const float*)d_in[4];
  const float* Wf = (const float*)d_in[5];
  const float* bf = (const float*)d_in[6];
  const float* lnf_s = (const float*)d_in[7];
  const float* lnf_b = (const float*)d_in[8];
  float* out = (float*)d_out;

  char* ws = (char*)d_ws;
  unsigned short* slotA = (unsigned short*)ws;                   // 25165824 B
  unsigned short* Vt = (unsigned short*)(ws + 25165824);         // 25165824 B
  unsigned short* Cbf = (unsigned short*)(ws + 50331648);        // 25165824 B
  float* g = (float*)(ws + 25165824);                            // 50331648 B (reuses Vt+Cbf)
  unsigned short* W2t = (unsigned short*)(ws + 75497472);        // 1179648 B
  unsigned short* Wft = (unsigned short*)(ws + 76677120);        // 2359296 B

  pack_w2t<<<2304, 256, 0, stream>>>(Wv, W2t);
  pack_wft<<<4608, 256, 0, stream>>>(Wf, Wft);
  pack_c<<<49152, 256, 0, stream>>>(alpha, Cbf);

  ln1_kernel<<<4096, 256, 0, stream>>>(x, ln1_s, ln1_b, slotA);
  gemm1_kernel<<<768, 256, 0, stream>>>(slotA, W2t, Vt);
  circ_kernel<<<768, 256, 0, stream>>>(Cbf, Vt, x, out, slotA);
  gemmf_kernel<<<768, 256, 0, stream>>>(slotA, Wft, bf, g);
  lnswish_kernel<<<4096, 256, 0, stream>>>(g, lnf_s, lnf_b, slotA);
  gemmf_kernel<<<768, 256, 0, stream>>>(slotA, Wft + 589824, bf + 768, g);
  final_kernel<<<4096, 256, 0, stream>>>(g, lnf_s + 768, lnf_b + 768, out);
}

// Round 4
// 351.035 us; speedup vs baseline: 1.0952x; 1.0118x over previous
//
#include <hip/hip_runtime.h>
#include <cstdint>
#include <cstddef>

// Problem constants: B=16, N=1024, D=768, H=12, HS=64, L=2
// Pipeline:
//  pack W2t/Wft/C (bf16, B^T layouts) ; LN1 -> xn(bf16)
//  GEMM1: xn(16384x768) @ W2t -> Vt[h][b*64+k][n]  (bf16)
//  circGEMM (per head h): C_h(1024x1024) @ Vt_h^T -> y ; x2 = x + y (f32 in d_out, bf16 copy)
//  GEMM2: x2 @ Wf0t + bf0 -> g (f32) ; LN+swish -> z1 (bf16)
//  GEMM3: z1 @ Wf1t + bf1 -> g ; final: LN+swish + x2, log_cosh -> d_out
//
// R4 changes vs R3 (diagnosis: per-iter barrier drain at L3 latency, 87% MFMA idle):
//  - gemm_core: double-buffered LDS (2x16KB) with prefetch of K-tile k+1 issued
//    BEFORE computing tile k -> ds_read+MFMA body overlaps load latency; the
//    __syncthreads vmcnt(0) drain only pays the residue.
//  - XOR LDS swizzle (source-side column-group permute, read-side XOR) kills
//    the 8-way ds_read_b128 bank conflict (-> 2-way = free per m136).
//
// ws layout (bytes):
//  [0, 25165824)           slotA  : xn_bf16 -> x2_bf16 -> z1_bf16
//  [25165824, 50331648)    Vt     : 12*1024*1024 bf16          } later reused
//  [50331648, 75497472)    Cbf    : 12*1024*1024 bf16          } as g (f32, 50MB)
//  [75497472, 76677120)    W2t    : 768*768 bf16
//  [76677120, 79036416)    Wft    : 2*768*768 bf16
// total 79,036,416 B

typedef __attribute__((ext_vector_type(8))) short bf16x8;
typedef __attribute__((ext_vector_type(4))) float f32x4;
typedef __attribute__((ext_vector_type(4))) unsigned short us4;

__device__ __forceinline__ unsigned short f2bf(float f) {
  unsigned int u = __builtin_bit_cast(unsigned int, f);
  u += 0x7FFFu + ((u >> 16) & 1u);   // round-to-nearest-even
  return (unsigned short)(u >> 16);
}

// async global->LDS, 16 bytes per lane; LDS dest is wave-uniform base + lane*16.
__device__ __forceinline__ void g2l16(const void* g, void* l) {
  __builtin_amdgcn_global_load_lds(
      (const __attribute__((address_space(1))) unsigned int*)g,
      (__attribute__((address_space(3))) unsigned int*)l,
      16, 0, 0);
}

// ---------------- pack kernels ----------------
__global__ __launch_bounds__(256) void pack_w2t(const float* __restrict__ Wv,
                                                unsigned short* __restrict__ W2t) {
  int o = blockIdx.x * 256 + threadIdx.x;   // < 589824
  int np = o / 768, d = o - np * 768;
  int h = np >> 6, k = np & 63;
  W2t[o] = f2bf(Wv[h * 49152 + d * 64 + k]);   // Wv[h][d][k]
}

__global__ __launch_bounds__(256) void pack_wft(const float* __restrict__ Wf,
                                                unsigned short* __restrict__ Wft) {
  int o = blockIdx.x * 256 + threadIdx.x;   // < 1179648
  int l = o / 589824, rem = o - l * 589824;
  int np = rem / 768, d = rem - np * 768;
  Wft[o] = f2bf(Wf[l * 589824 + d * 768 + np]);  // Wf[l][d][np]
}

__global__ __launch_bounds__(256) void pack_c(const float* __restrict__ alpha,
                                              unsigned short* __restrict__ Cbf) {
  int o = blockIdx.x * 256 + threadIdx.x;   // < 12582912
  int h = o >> 20, i = (o >> 10) & 1023, j = o & 1023;
  Cbf[o] = f2bf(alpha[(h << 10) + ((i - j) & 1023)]);
}

// ---------------- row kernels: 1 wave per row (D=768 = 64 lanes x 3 float4)
__device__ __forceinline__ void wave_reduce2(float& s, float& s2) {
#pragma unroll
  for (int off = 32; off > 0; off >>= 1) {
    s += __shfl_down(s, off);
    s2 += __shfl_down(s2, off);
  }
  s = __shfl(s, 0);
  s2 = __shfl(s2, 0);
}

__global__ __launch_bounds__(256) void ln1_kernel(const float* __restrict__ x,
                                                  const float* __restrict__ sc,
                                                  const float* __restrict__ bi,
                                                  unsigned short* __restrict__ out) {
  int row = blockIdx.x * 4 + (threadIdx.x >> 6);
  int lane = threadIdx.x & 63;
  size_t base = (size_t)row * 768;
  float4 v[3];
#pragma unroll
  for (int j = 0; j < 3; ++j) v[j] = *(const float4*)(x + base + lane * 4 + j * 256);
  float s = 0.f, s2 = 0.f;
#pragma unroll
  for (int j = 0; j < 3; ++j) {
    s += v[j].x + v[j].y + v[j].z + v[j].w;
    s2 += v[j].x * v[j].x + v[j].y * v[j].y + v[j].z * v[j].z + v[j].w * v[j].w;
  }
  wave_reduce2(s, s2);
  float mu = s * (1.0f / 768.0f);
  float var = s2 * (1.0f / 768.0f) - mu * mu;
  float r = rsqrtf(var + 1e-6f);
#pragma unroll
  for (int j = 0; j < 3; ++j) {
    int d = lane * 4 + j * 256;
    float4 scv = *(const float4*)(sc + d);
    float4 biv = *(const float4*)(bi + d);
    us4 o;
    o[0] = f2bf((v[j].x - mu) * r * scv.x + biv.x);
    o[1] = f2bf((v[j].y - mu) * r * scv.y + biv.y);
    o[2] = f2bf((v[j].z - mu) * r * scv.z + biv.z);
    o[3] = f2bf((v[j].w - mu) * r * scv.w + biv.w);
    *(us4*)(out + base + d) = o;
  }
}

__global__ __launch_bounds__(256) void lnswish_kernel(const float* __restrict__ g,
                                                      const float* __restrict__ sc,
                                                      const float* __restrict__ bi,
                                                      unsigned short* __restrict__ out) {
  int row = blockIdx.x * 4 + (threadIdx.x >> 6);
  int lane = threadIdx.x & 63;
  size_t base = (size_t)row * 768;
  float4 v[3];
#pragma unroll
  for (int j = 0; j < 3; ++j) v[j] = *(const float4*)(g + base + lane * 4 + j * 256);
  float s = 0.f, s2 = 0.f;
#pragma unroll
  for (int j = 0; j < 3; ++j) {
    s += v[j].x + v[j].y + v[j].z + v[j].w;
    s2 += v[j].x * v[j].x + v[j].y * v[j].y + v[j].z * v[j].z + v[j].w * v[j].w;
  }
  wave_reduce2(s, s2);
  float mu = s * (1.0f / 768.0f);
  float var = s2 * (1.0f / 768.0f) - mu * mu;
  float r = rsqrtf(var + 1e-6f);
#pragma unroll
  for (int j = 0; j < 3; ++j) {
    int d = lane * 4 + j * 256;
    float4 scv = *(const float4*)(sc + d);
    float4 biv = *(const float4*)(bi + d);
    float zz[4] = {(v[j].x - mu) * r * scv.x + biv.x, (v[j].y - mu) * r * scv.y + biv.y,
                   (v[j].z - mu) * r * scv.z + biv.z, (v[j].w - mu) * r * scv.w + biv.w};
    us4 o;
#pragma unroll
    for (int q = 0; q < 4; ++q) o[q] = f2bf(zz[q] / (1.0f + expf(-zz[q])));
    *(us4*)(out + base + d) = o;
  }
}

__global__ __launch_bounds__(256) void final_kernel(const float* __restrict__ g,
                                                    const float* __restrict__ sc,
                                                    const float* __restrict__ bi,
                                                    float* __restrict__ out) {
  int row = blockIdx.x * 4 + (threadIdx.x >> 6);
  int lane = threadIdx.x & 63;
  size_t base = (size_t)row * 768;
  float4 v[3];
#pragma unroll
  for (int j = 0; j < 3; ++j) v[j] = *(const float4*)(g + base + lane * 4 + j * 256);
  float s = 0.f, s2 = 0.f;
#pragma unroll
  for (int j = 0; j < 3; ++j) {
    s += v[j].x + v[j].y + v[j].z + v[j].w;
    s2 += v[j].x * v[j].x + v[j].y * v[j].y + v[j].z * v[j].z + v[j].w * v[j].w;
  }
  wave_reduce2(s, s2);
  float mu = s * (1.0f / 768.0f);
  float var = s2 * (1.0f / 768.0f) - mu * mu;
  float r = rsqrtf(var + 1e-6f);
#pragma unroll
  for (int j = 0; j < 3; ++j) {
    int d = lane * 4 + j * 256;
    float4 scv = *(const float4*)(sc + d);
    float4 biv = *(const float4*)(bi + d);
    float4 xv = *(const float4*)(out + base + d);   // x2 stored in d_out
    float zz[4] = {(v[j].x - mu) * r * scv.x + biv.x, (v[j].y - mu) * r * scv.y + biv.y,
                   (v[j].z - mu) * r * scv.z + biv.z, (v[j].w - mu) * r * scv.w + biv.w};
    float xx[4] = {xv.x, xv.y, xv.z, xv.w};
    float4 o;
    float* op = &o.x;
#pragma unroll
    for (int q = 0; q < 4; ++q) {
      float sw = zz[q] / (1.0f + expf(-zz[q]));
      float t = sw + xx[q];
      float ax = fabsf(t);
      op[q] = ax + log1pf(expf(-2.0f * ax)) - 0.69314718055994531f;
    }
    *(float4*)(out + base + d) = o;
  }
}

// ---------------- MFMA GEMM core: 128x128 tile, BK=32, 4 waves ------------
// Double-buffered LDS + prefetch-before-compute; XOR-swizzled LDS layout.
// A: MxK row-major bf16 ; Bt: NxK row-major bf16.
// LDS slot (row, cg) holds global column-group cg ^ ((row>>1)&3); the
// global_load_lds dest stays strictly lane-ordered (base + lane*16).
__device__ __forceinline__ void gemm_core(const unsigned short* __restrict__ A,
                                          const unsigned short* __restrict__ Bt,
                                          int K, int m0, int n0,
                                          unsigned short* sA, unsigned short* sB,
                                          f32x4 acc[4][4]) {
  const int tid = threadIdx.x;
  const int wave = tid >> 6, lane = tid & 63;
  const int wm = (wave >> 1) << 6, wn = (wave & 1) << 6;
  const int fm = lane & 15, fq = lane >> 4;
  const int r0 = tid >> 2, r1 = (tid >> 2) + 64;   // staged rows
  const int cg = tid & 3;
  const int cs0 = (cg ^ ((r0 >> 1) & 3)) << 3;     // src col-group (elems)
  const int cs1 = (cg ^ ((r1 >> 1) & 3)) << 3;
  const int ld0 = r0 * 32 + (cg << 3);             // LDS slot (elems)
  const int ld1 = r1 * 32 + (cg << 3);

  const int niter = K >> 5;
#define STAGE(k0, buf)                                                        \
  {                                                                           \
    unsigned short* dA = sA + (buf) * 4096;                                   \
    unsigned short* dB = sB + (buf) * 4096;                                   \
    g2l16(A + (size_t)(m0 + r0) * K + (k0) + cs0, dA + ld0);                  \
    g2l16(Bt + (size_t)(n0 + r0) * K + (k0) + cs0, dB + ld0);                 \
    g2l16(A + (size_t)(m0 + r1) * K + (k0) + cs1, dA + ld1);                  \
    g2l16(Bt + (size_t)(n0 + r1) * K + (k0) + cs1, dB + ld1);                 \
  }

  STAGE(0, 0);
  for (int it = 0; it < niter; ++it) {
    int buf = it & 1;
    __syncthreads();                       // drains vmcnt: buf's loads done
    if (it + 1 < niter) STAGE((it + 1) << 5, buf ^ 1);  // prefetch overlaps compute
    const unsigned short* pA = sA + buf * 4096;
    const unsigned short* pB = sB + buf * 4096;
    bf16x8 aq[4], bq[4];
#pragma unroll
    for (int t = 0; t < 4; ++t) {
      int ra = wm + (t << 4) + fm;
      int rb = wn + (t << 4) + fm;
      aq[t] = *(const bf16x8*)(pA + (ra << 5) + ((fq ^ ((ra >> 1) & 3)) << 3));
      bq[t] = *(const bf16x8*)(pB + (rb << 5) + ((fq ^ ((rb >> 1) & 3)) << 3));
    }
#pragma unroll
    for (int mt = 0; mt < 4; ++mt)
#pragma unroll
      for (int nt = 0; nt < 4; ++nt)
        acc[mt][nt] = __builtin_amdgcn_mfma_f32_16x16x32_bf16(aq[mt], bq[nt],
                                                              acc[mt][nt], 0, 0, 0);
  }
#undef STAGE
}

// XCD-swizzled decode for 16384x768-output GEMMs (128 m-tiles x 6 n-tiles).
// Each XCD (= flat%8) owns m-strips {xcd, xcd+8, ...}: A 3MB + B 1.2MB in L2.
__device__ __forceinline__ void decode_mn_768(int f, int& m0, int& n0) {
  int xcd = f & 7, s = f >> 3;        // s in [0,96)
  int g = s / 6, bx = s - g * 6;      // g in [0,16)
  m0 = (xcd + g * 8) << 7;
  n0 = bx << 7;
}

// GEMM1: xn @ W2t -> Vt[h][b*64+k][n] (bf16)
__global__ __launch_bounds__(256) void gemm1_kernel(const unsigned short* __restrict__ A,
                                                    const unsigned short* __restrict__ Bt,
                                                    unsigned short* __restrict__ Vt) {
  __shared__ unsigned short sA[2 * 128 * 32];
  __shared__ unsigned short sB[2 * 128 * 32];
  f32x4 acc[4][4] = {};
  int m0, n0;
  decode_mn_768(blockIdx.x, m0, n0);
  gemm_core(A, Bt, 768, m0, n0, sA, sB, acc);
  const int wave = threadIdx.x >> 6, lane = threadIdx.x & 63;
  const int wm = (wave >> 1) << 6, wn = (wave & 1) << 6;
  const int fm = lane & 15, fq = lane >> 4;
#pragma unroll
  for (int mt = 0; mt < 4; ++mt) {
    int rowb = m0 + wm + (mt << 4) + (fq << 2);   // 4 consecutive rows
    int b = rowb >> 10, n = rowb & 1023;
#pragma unroll
    for (int nt = 0; nt < 4; ++nt) {
      int col = n0 + wn + (nt << 4) + fm;
      int h = col >> 6, ck = col & 63;
      size_t off = ((size_t)h << 20) + (size_t)((b << 6) + ck) * 1024 + n;
      us4 v;
#pragma unroll
      for (int r = 0; r < 4; ++r) v[r] = f2bf(acc[mt][nt][r]);
      *(us4*)(Vt + off) = v;
    }
  }
}

// circGEMM: per head, C_h @ V_h ; epilogue x2 = x + y
__global__ __launch_bounds__(256) void circ_kernel(const unsigned short* __restrict__ Cbf,
                                                   const unsigned short* __restrict__ Vt,
                                                   const float* __restrict__ xin,
                                                   float* __restrict__ x2f,
                                                   unsigned short* __restrict__ x2bf) {
  __shared__ unsigned short sA[2 * 128 * 32];
  __shared__ unsigned short sB[2 * 128 * 32];
  f32x4 acc[4][4] = {};
  int f = blockIdx.x;                 // [0,768)
  int xcd = f & 7, s = f >> 3;        // s in [0,96)
  int h = s >> 3, t = s & 7;          // 12 heads x 8 tiles-per-XCD-per-head
  int mr = xcd >> 1, nr = xcd & 1;    // region: 2 m-tiles x 4 n-tiles
  int m0 = ((mr << 1) + (t >> 2)) << 7;
  int n0 = ((nr << 2) + (t & 3)) << 7;
  gemm_core(Cbf + ((size_t)h << 20), Vt + ((size_t)h << 20), 1024, m0, n0, sA, sB, acc);
  const int wave = threadIdx.x >> 6, lane = threadIdx.x & 63;
  const int wm = (wave >> 1) << 6, wn = (wave & 1) << 6;
  const int fm = lane & 15, fq = lane >> 4;
#pragma unroll
  for (int mt = 0; mt < 4; ++mt) {
    int ib = m0 + wm + (mt << 4) + (fq << 2);
#pragma unroll
    for (int nt = 0; nt < 4; ++nt) {
      int c = n0 + wn + (nt << 4) + fm;
      int b = c >> 6, k = c & 63;
      size_t off = ((size_t)(b << 10) + ib) * 768 + (h << 6) + k;
#pragma unroll
      for (int r = 0; r < 4; ++r) {
        float val = acc[mt][nt][r] + xin[off + (size_t)r * 768];
        x2f[off + (size_t)r * 768] = val;
        x2bf[off + (size_t)r * 768] = f2bf(val);
      }
    }
  }
}

// FFN GEMM: A @ Wt + bias -> g (f32)
__global__ __launch_bounds__(256) void gemmf_kernel(const unsigned short* __restrict__ A,
                                                    const unsigned short* __restrict__ Bt,
                                                    const float* __restrict__ bias,
                                                    float* __restrict__ g) {
  __shared__ unsigned short sA[2 * 128 * 32];
  __shared__ unsigned short sB[2 * 128 * 32];
  f32x4 acc[4][4] = {};
  int m0, n0;
  decode_mn_768(blockIdx.x, m0, n0);
  gemm_core(A, Bt, 768, m0, n0, sA, sB, acc);
  const int wave = threadIdx.x >> 6, lane = threadIdx.x & 63;
  const int wm = (wave >> 1) << 6, wn = (wave & 1) << 6;
  const int fm = lane & 15, fq = lane >> 4;
#pragma unroll
  for (int mt = 0; mt < 4; ++mt) {
    int rowb = m0 + wm + (mt << 4) + (fq << 2);
#pragma unroll
    for (int nt = 0; nt < 4; ++nt) {
      int col = n0 + wn + (nt << 4) + fm;
      float bc = bias[col];
#pragma unroll
      for (int r = 0; r < 4; ++r)
        g[(size_t)(rowb + r) * 768 + col] = acc[mt][nt][r] + bc;
    }
  }
}

extern "C" void kernel_launch(void* const* d_in, const int* in_sizes, int n_in,
                              void* d_out, int out_size, void* d_ws, size_t ws_size,
                              hipStream_t stream) {
  const float* x = (const float*)d_in[0];
  const float* ln1_s = (const float*)d_in[1];
  const float* ln1_b = (const float*)d_in[2];
  const float* Wv = (const float*)d_in[3];
  const float* alpha = (const float*)d_in[4];
  const float* Wf = (const float*)d_in[5];
  const float* bf = (const float*)d_in[6];
  const float* lnf_s = (const float*)d_in[7];
  const float* lnf_b = (const float*)d_in[8];
  float* out = (float*)d_out;

  char* ws = (char*)d_ws;
  unsigned short* slotA = (unsigned short*)ws;                   // 25165824 B
  unsigned short* Vt = (unsigned short*)(ws + 25165824);         // 25165824 B
  unsigned short* Cbf = (unsigned short*)(ws + 50331648);        // 25165824 B
  float* g = (float*)(ws + 25165824);                            // 50331648 B (reuses Vt+Cbf)
  unsigned short* W2t = (unsigned short*)(ws + 75497472);        // 1179648 B
  unsigned short* Wft = (unsigned short*)(ws + 76677120);        // 2359296 B

  pack_w2t<<<2304, 256, 0, stream>>>(Wv, W2t);
  pack_wft<<<4608, 256, 0, stream>>>(Wf, Wft);
  pack_c<<<49152, 256, 0, stream>>>(alpha, Cbf);

  ln1_kernel<<<4096, 256, 0, stream>>>(x, ln1_s, ln1_b, slotA);
  gemm1_kernel<<<768, 256, 0, stream>>>(slotA, W2t, Vt);
  circ_kernel<<<768, 256, 0, stream>>>(Cbf, Vt, x, out, slotA);
  gemmf_kernel<<<768, 256, 0, stream>>>(slotA, Wft, bf, g);
  lnswish_kernel<<<4096, 256, 0, stream>>>(g, lnf_s, lnf_b, slotA);
  gemmf_kernel<<<768, 256, 0, stream>>>(slotA, Wft + 589824, bf + 768, g);
  final_kernel<<<4096, 256, 0, stream>>>(g, lnf_s + 768, lnf_b + 768, out);
}

// Round 5
// 316.118 us; speedup vs baseline: 1.2161x; 1.1105x over previous
//
#include <hip/hip_runtime.h>
#include <cstdint>
#include <cstddef>

// Problem constants: B=16, N=1024, D=768, H=12, HS=64, L=2
// Pipeline:
//  pack W2t/Wft/C (bf16, B^T layouts) ; LN1 -> xn(bf16)
//  GEMM1: xn(16384x768) @ W2t -> Vt[h][b*64+k][n]  (bf16)
//  circGEMM (per head h): C_h(1024x1024) @ Vt_h^T -> y ; x2 = x + y (f32 in d_out, bf16 copy)
//  GEMM2: x2 @ Wf0t + bf0 -> g (f32) ; LN+swish -> z1 (bf16)
//  GEMM3: z1 @ Wf1t + bf1 -> g ; final: LN+swish + x2, log_cosh -> d_out
//
// R5 changes vs R4:
//  - lnswish/final: libm expf/log1pf -> __expf/__logf (v_exp_f32/v_log_f32);
//    final was 57us vs 24us roofline, diagnosed libm-VALU-bound.
//  - GEMM kernels: __launch_bounds__(256,4) -> 4 blocks/CU resident (VGPR 72
//    fits the 128 cap; LDS 4x32KB=128<=160KB) to hide prefetch residue.
//
// ws layout (bytes):
//  [0, 25165824)           slotA  : xn_bf16 -> x2_bf16 -> z1_bf16
//  [25165824, 50331648)    Vt     : 12*1024*1024 bf16          } later reused
//  [50331648, 75497472)    Cbf    : 12*1024*1024 bf16          } as g (f32, 50MB)
//  [75497472, 76677120)    W2t    : 768*768 bf16
//  [76677120, 79036416)    Wft    : 2*768*768 bf16
// total 79,036,416 B

typedef __attribute__((ext_vector_type(8))) short bf16x8;
typedef __attribute__((ext_vector_type(4))) float f32x4;
typedef __attribute__((ext_vector_type(4))) unsigned short us4;

__device__ __forceinline__ unsigned short f2bf(float f) {
  unsigned int u = __builtin_bit_cast(unsigned int, f);
  u += 0x7FFFu + ((u >> 16) & 1u);   // round-to-nearest-even
  return (unsigned short)(u >> 16);
}

// async global->LDS, 16 bytes per lane; LDS dest is wave-uniform base + lane*16.
__device__ __forceinline__ void g2l16(const void* g, void* l) {
  __builtin_amdgcn_global_load_lds(
      (const __attribute__((address_space(1))) unsigned int*)g,
      (__attribute__((address_space(3))) unsigned int*)l,
      16, 0, 0);
}

// ---------------- pack kernels ----------------
__global__ __launch_bounds__(256) void pack_w2t(const float* __restrict__ Wv,
                                                unsigned short* __restrict__ W2t) {
  int o = blockIdx.x * 256 + threadIdx.x;   // < 589824
  int np = o / 768, d = o - np * 768;
  int h = np >> 6, k = np & 63;
  W2t[o] = f2bf(Wv[h * 49152 + d * 64 + k]);   // Wv[h][d][k]
}

__global__ __launch_bounds__(256) void pack_wft(const float* __restrict__ Wf,
                                                unsigned short* __restrict__ Wft) {
  int o = blockIdx.x * 256 + threadIdx.x;   // < 1179648
  int l = o / 589824, rem = o - l * 589824;
  int np = rem / 768, d = rem - np * 768;
  Wft[o] = f2bf(Wf[l * 589824 + d * 768 + np]);  // Wf[l][d][np]
}

__global__ __launch_bounds__(256) void pack_c(const float* __restrict__ alpha,
                                              unsigned short* __restrict__ Cbf) {
  int o = blockIdx.x * 256 + threadIdx.x;   // < 12582912
  int h = o >> 20, i = (o >> 10) & 1023, j = o & 1023;
  Cbf[o] = f2bf(alpha[(h << 10) + ((i - j) & 1023)]);
}

// ---------------- row kernels: 1 wave per row (D=768 = 64 lanes x 3 float4)
__device__ __forceinline__ void wave_reduce2(float& s, float& s2) {
#pragma unroll
  for (int off = 32; off > 0; off >>= 1) {
    s += __shfl_down(s, off);
    s2 += __shfl_down(s2, off);
  }
  s = __shfl(s, 0);
  s2 = __shfl(s2, 0);
}

__global__ __launch_bounds__(256) void ln1_kernel(const float* __restrict__ x,
                                                  const float* __restrict__ sc,
                                                  const float* __restrict__ bi,
                                                  unsigned short* __restrict__ out) {
  int row = blockIdx.x * 4 + (threadIdx.x >> 6);
  int lane = threadIdx.x & 63;
  size_t base = (size_t)row * 768;
  float4 v[3];
#pragma unroll
  for (int j = 0; j < 3; ++j) v[j] = *(const float4*)(x + base + lane * 4 + j * 256);
  float s = 0.f, s2 = 0.f;
#pragma unroll
  for (int j = 0; j < 3; ++j) {
    s += v[j].x + v[j].y + v[j].z + v[j].w;
    s2 += v[j].x * v[j].x + v[j].y * v[j].y + v[j].z * v[j].z + v[j].w * v[j].w;
  }
  wave_reduce2(s, s2);
  float mu = s * (1.0f / 768.0f);
  float var = s2 * (1.0f / 768.0f) - mu * mu;
  float r = rsqrtf(var + 1e-6f);
#pragma unroll
  for (int j = 0; j < 3; ++j) {
    int d = lane * 4 + j * 256;
    float4 scv = *(const float4*)(sc + d);
    float4 biv = *(const float4*)(bi + d);
    us4 o;
    o[0] = f2bf((v[j].x - mu) * r * scv.x + biv.x);
    o[1] = f2bf((v[j].y - mu) * r * scv.y + biv.y);
    o[2] = f2bf((v[j].z - mu) * r * scv.z + biv.z);
    o[3] = f2bf((v[j].w - mu) * r * scv.w + biv.w);
    *(us4*)(out + base + d) = o;
  }
}

__global__ __launch_bounds__(256) void lnswish_kernel(const float* __restrict__ g,
                                                      const float* __restrict__ sc,
                                                      const float* __restrict__ bi,
                                                      unsigned short* __restrict__ out) {
  int row = blockIdx.x * 4 + (threadIdx.x >> 6);
  int lane = threadIdx.x & 63;
  size_t base = (size_t)row * 768;
  float4 v[3];
#pragma unroll
  for (int j = 0; j < 3; ++j) v[j] = *(const float4*)(g + base + lane * 4 + j * 256);
  float s = 0.f, s2 = 0.f;
#pragma unroll
  for (int j = 0; j < 3; ++j) {
    s += v[j].x + v[j].y + v[j].z + v[j].w;
    s2 += v[j].x * v[j].x + v[j].y * v[j].y + v[j].z * v[j].z + v[j].w * v[j].w;
  }
  wave_reduce2(s, s2);
  float mu = s * (1.0f / 768.0f);
  float var = s2 * (1.0f / 768.0f) - mu * mu;
  float r = rsqrtf(var + 1e-6f);
#pragma unroll
  for (int j = 0; j < 3; ++j) {
    int d = lane * 4 + j * 256;
    float4 scv = *(const float4*)(sc + d);
    float4 biv = *(const float4*)(bi + d);
    float zz[4] = {(v[j].x - mu) * r * scv.x + biv.x, (v[j].y - mu) * r * scv.y + biv.y,
                   (v[j].z - mu) * r * scv.z + biv.z, (v[j].w - mu) * r * scv.w + biv.w};
    us4 o;
#pragma unroll
    for (int q = 0; q < 4; ++q) o[q] = f2bf(zz[q] / (1.0f + __expf(-zz[q])));
    *(us4*)(out + base + d) = o;
  }
}

__global__ __launch_bounds__(256) void final_kernel(const float* __restrict__ g,
                                                    const float* __restrict__ sc,
                                                    const float* __restrict__ bi,
                                                    float* __restrict__ out) {
  int row = blockIdx.x * 4 + (threadIdx.x >> 6);
  int lane = threadIdx.x & 63;
  size_t base = (size_t)row * 768;
  float4 v[3];
#pragma unroll
  for (int j = 0; j < 3; ++j) v[j] = *(const float4*)(g + base + lane * 4 + j * 256);
  float s = 0.f, s2 = 0.f;
#pragma unroll
  for (int j = 0; j < 3; ++j) {
    s += v[j].x + v[j].y + v[j].z + v[j].w;
    s2 += v[j].x * v[j].x + v[j].y * v[j].y + v[j].z * v[j].z + v[j].w * v[j].w;
  }
  wave_reduce2(s, s2);
  float mu = s * (1.0f / 768.0f);
  float var = s2 * (1.0f / 768.0f) - mu * mu;
  float r = rsqrtf(var + 1e-6f);
#pragma unroll
  for (int j = 0; j < 3; ++j) {
    int d = lane * 4 + j * 256;
    float4 scv = *(const float4*)(sc + d);
    float4 biv = *(const float4*)(bi + d);
    float4 xv = *(const float4*)(out + base + d);   // x2 stored in d_out
    float zz[4] = {(v[j].x - mu) * r * scv.x + biv.x, (v[j].y - mu) * r * scv.y + biv.y,
                   (v[j].z - mu) * r * scv.z + biv.z, (v[j].w - mu) * r * scv.w + biv.w};
    float xx[4] = {xv.x, xv.y, xv.z, xv.w};
    float4 o;
    float* op = &o.x;
#pragma unroll
    for (int q = 0; q < 4; ++q) {
      float sw = zz[q] / (1.0f + __expf(-zz[q]));
      float t = sw + xx[q];
      float ax = fabsf(t);
      op[q] = ax + __logf(1.0f + __expf(-2.0f * ax)) - 0.69314718055994531f;
    }
    *(float4*)(out + base + d) = o;
  }
}

// ---------------- MFMA GEMM core: 128x128 tile, BK=32, 4 waves ------------
// Double-buffered LDS + prefetch-before-compute; XOR-swizzled LDS layout.
// A: MxK row-major bf16 ; Bt: NxK row-major bf16.
// LDS slot (row, cg) holds global column-group cg ^ ((row>>1)&3); the
// global_load_lds dest stays strictly lane-ordered (base + lane*16).
__device__ __forceinline__ void gemm_core(const unsigned short* __restrict__ A,
                                          const unsigned short* __restrict__ Bt,
                                          int K, int m0, int n0,
                                          unsigned short* sA, unsigned short* sB,
                                          f32x4 acc[4][4]) {
  const int tid = threadIdx.x;
  const int wave = tid >> 6, lane = tid & 63;
  const int wm = (wave >> 1) << 6, wn = (wave & 1) << 6;
  const int fm = lane & 15, fq = lane >> 4;
  const int r0 = tid >> 2, r1 = (tid >> 2) + 64;   // staged rows
  const int cg = tid & 3;
  const int cs0 = (cg ^ ((r0 >> 1) & 3)) << 3;     // src col-group (elems)
  const int cs1 = (cg ^ ((r1 >> 1) & 3)) << 3;
  const int ld0 = r0 * 32 + (cg << 3);             // LDS slot (elems)
  const int ld1 = r1 * 32 + (cg << 3);

  const int niter = K >> 5;
#define STAGE(k0, buf)                                                        \
  {                                                                           \
    unsigned short* dA = sA + (buf) * 4096;                                   \
    unsigned short* dB = sB + (buf) * 4096;                                   \
    g2l16(A + (size_t)(m0 + r0) * K + (k0) + cs0, dA + ld0);                  \
    g2l16(Bt + (size_t)(n0 + r0) * K + (k0) + cs0, dB + ld0);                 \
    g2l16(A + (size_t)(m0 + r1) * K + (k0) + cs1, dA + ld1);                  \
    g2l16(Bt + (size_t)(n0 + r1) * K + (k0) + cs1, dB + ld1);                 \
  }

  STAGE(0, 0);
  for (int it = 0; it < niter; ++it) {
    int buf = it & 1;
    __syncthreads();                       // drains vmcnt: buf's loads done
    if (it + 1 < niter) STAGE((it + 1) << 5, buf ^ 1);  // prefetch overlaps compute
    const unsigned short* pA = sA + buf * 4096;
    const unsigned short* pB = sB + buf * 4096;
    bf16x8 aq[4], bq[4];
#pragma unroll
    for (int t = 0; t < 4; ++t) {
      int ra = wm + (t << 4) + fm;
      int rb = wn + (t << 4) + fm;
      aq[t] = *(const bf16x8*)(pA + (ra << 5) + ((fq ^ ((ra >> 1) & 3)) << 3));
      bq[t] = *(const bf16x8*)(pB + (rb << 5) + ((fq ^ ((rb >> 1) & 3)) << 3));
    }
#pragma unroll
    for (int mt = 0; mt < 4; ++mt)
#pragma unroll
      for (int nt = 0; nt < 4; ++nt)
        acc[mt][nt] = __builtin_amdgcn_mfma_f32_16x16x32_bf16(aq[mt], bq[nt],
                                                              acc[mt][nt], 0, 0, 0);
  }
#undef STAGE
}

// XCD-swizzled decode for 16384x768-output GEMMs (128 m-tiles x 6 n-tiles).
// Each XCD (= flat%8) owns m-strips {xcd, xcd+8, ...}: A 3MB + B 1.2MB in L2.
__device__ __forceinline__ void decode_mn_768(int f, int& m0, int& n0) {
  int xcd = f & 7, s = f >> 3;        // s in [0,96)
  int g = s / 6, bx = s - g * 6;      // g in [0,16)
  m0 = (xcd + g * 8) << 7;
  n0 = bx << 7;
}

// GEMM1: xn @ W2t -> Vt[h][b*64+k][n] (bf16)
__global__ __launch_bounds__(256, 4) void gemm1_kernel(const unsigned short* __restrict__ A,
                                                       const unsigned short* __restrict__ Bt,
                                                       unsigned short* __restrict__ Vt) {
  __shared__ unsigned short sA[2 * 128 * 32];
  __shared__ unsigned short sB[2 * 128 * 32];
  f32x4 acc[4][4] = {};
  int m0, n0;
  decode_mn_768(blockIdx.x, m0, n0);
  gemm_core(A, Bt, 768, m0, n0, sA, sB, acc);
  const int wave = threadIdx.x >> 6, lane = threadIdx.x & 63;
  const int wm = (wave >> 1) << 6, wn = (wave & 1) << 6;
  const int fm = lane & 15, fq = lane >> 4;
#pragma unroll
  for (int mt = 0; mt < 4; ++mt) {
    int rowb = m0 + wm + (mt << 4) + (fq << 2);   // 4 consecutive rows
    int b = rowb >> 10, n = rowb & 1023;
#pragma unroll
    for (int nt = 0; nt < 4; ++nt) {
      int col = n0 + wn + (nt << 4) + fm;
      int h = col >> 6, ck = col & 63;
      size_t off = ((size_t)h << 20) + (size_t)((b << 6) + ck) * 1024 + n;
      us4 v;
#pragma unroll
      for (int r = 0; r < 4; ++r) v[r] = f2bf(acc[mt][nt][r]);
      *(us4*)(Vt + off) = v;
    }
  }
}

// circGEMM: per head, C_h @ V_h ; epilogue x2 = x + y
__global__ __launch_bounds__(256, 4) void circ_kernel(const unsigned short* __restrict__ Cbf,
                                                      const unsigned short* __restrict__ Vt,
                                                      const float* __restrict__ xin,
                                                      float* __restrict__ x2f,
                                                      unsigned short* __restrict__ x2bf) {
  __shared__ unsigned short sA[2 * 128 * 32];
  __shared__ unsigned short sB[2 * 128 * 32];
  f32x4 acc[4][4] = {};
  int f = blockIdx.x;                 // [0,768)
  int xcd = f & 7, s = f >> 3;        // s in [0,96)
  int h = s >> 3, t = s & 7;          // 12 heads x 8 tiles-per-XCD-per-head
  int mr = xcd >> 1, nr = xcd & 1;    // region: 2 m-tiles x 4 n-tiles
  int m0 = ((mr << 1) + (t >> 2)) << 7;
  int n0 = ((nr << 2) + (t & 3)) << 7;
  gemm_core(Cbf + ((size_t)h << 20), Vt + ((size_t)h << 20), 1024, m0, n0, sA, sB, acc);
  const int wave = threadIdx.x >> 6, lane = threadIdx.x & 63;
  const int wm = (wave >> 1) << 6, wn = (wave & 1) << 6;
  const int fm = lane & 15, fq = lane >> 4;
#pragma unroll
  for (int mt = 0; mt < 4; ++mt) {
    int ib = m0 + wm + (mt << 4) + (fq << 2);
#pragma unroll
    for (int nt = 0; nt < 4; ++nt) {
      int c = n0 + wn + (nt << 4) + fm;
      int b = c >> 6, k = c & 63;
      size_t off = ((size_t)(b << 10) + ib) * 768 + (h << 6) + k;
#pragma unroll
      for (int r = 0; r < 4; ++r) {
        float val = acc[mt][nt][r] + xin[off + (size_t)r * 768];
        x2f[off + (size_t)r * 768] = val;
        x2bf[off + (size_t)r * 768] = f2bf(val);
      }
    }
  }
}

// FFN GEMM: A @ Wt + bias -> g (f32)
__global__ __launch_bounds__(256, 4) void gemmf_kernel(const unsigned short* __restrict__ A,
                                                       const unsigned short* __restrict__ Bt,
                                                       const float* __restrict__ bias,
                                                       float* __restrict__ g) {
  __shared__ unsigned short sA[2 * 128 * 32];
  __shared__ unsigned short sB[2 * 128 * 32];
  f32x4 acc[4][4] = {};
  int m0, n0;
  decode_mn_768(blockIdx.x, m0, n0);
  gemm_core(A, Bt, 768, m0, n0, sA, sB, acc);
  const int wave = threadIdx.x >> 6, lane = threadIdx.x & 63;
  const int wm = (wave >> 1) << 6, wn = (wave & 1) << 6;
  const int fm = lane & 15, fq = lane >> 4;
#pragma unroll
  for (int mt = 0; mt < 4; ++mt) {
    int rowb = m0 + wm + (mt << 4) + (fq << 2);
#pragma unroll
    for (int nt = 0; nt < 4; ++nt) {
      int col = n0 + wn + (nt << 4) + fm;
      float bc = bias[col];
#pragma unroll
      for (int r = 0; r < 4; ++r)
        g[(size_t)(rowb + r) * 768 + col] = acc[mt][nt][r] + bc;
    }
  }
}

extern "C" void kernel_launch(void* const* d_in, const int* in_sizes, int n_in,
                              void* d_out, int out_size, void* d_ws, size_t ws_size,
                              hipStream_t stream) {
  const float* x = (const float*)d_in[0];
  const float* ln1_s = (const float*)d_in[1];
  const float* ln1_b = (const float*)d_in[2];
  const float* Wv = (const float*)d_in[3];
  const float* alpha = (const float*)d_in[4];
  const float* Wf = (const float*)d_in[5];
  const float* bf = (const float*)d_in[6];
  const float* lnf_s = (const float*)d_in[7];
  const float* lnf_b = (const float*)d_in[8];
  float* out = (float*)d_out;

  char* ws = (char*)d_ws;
  unsigned short* slotA = (unsigned short*)ws;                   // 25165824 B
  unsigned short* Vt = (unsigned short*)(ws + 25165824);         // 25165824 B
  unsigned short* Cbf = (unsigned short*)(ws + 50331648);        // 25165824 B
  float* g = (float*)(ws + 25165824);                            // 50331648 B (reuses Vt+Cbf)
  unsigned short* W2t = (unsigned short*)(ws + 75497472);        // 1179648 B
  unsigned short* Wft = (unsigned short*)(ws + 76677120);        // 2359296 B

  pack_w2t<<<2304, 256, 0, stream>>>(Wv, W2t);
  pack_wft<<<4608, 256, 0, stream>>>(Wf, Wft);
  pack_c<<<49152, 256, 0, stream>>>(alpha, Cbf);

  ln1_kernel<<<4096, 256, 0, stream>>>(x, ln1_s, ln1_b, slotA);
  gemm1_kernel<<<768, 256, 0, stream>>>(slotA, W2t, Vt);
  circ_kernel<<<768, 256, 0, stream>>>(Cbf, Vt, x, out, slotA);
  gemmf_kernel<<<768, 256, 0, stream>>>(slotA, Wft, bf, g);
  lnswish_kernel<<<4096, 256, 0, stream>>>(g, lnf_s, lnf_b, slotA);
  gemmf_kernel<<<768, 256, 0, stream>>>(slotA, Wft + 589824, bf + 768, g);
  final_kernel<<<4096, 256, 0, stream>>>(g, lnf_s + 768, lnf_b + 768, out);
}

// Round 6
// 277.990 us; speedup vs baseline: 1.3830x; 1.1372x over previous
//
#include <hip/hip_runtime.h>
#include <cstdint>
#include <cstddef>

// B=16, N=1024, D=768, H=12, HS=64, L=2
// R6 changes vs R5:
//  - circ: C matrix never materialized. A-fragments come from 8 shifted LDS
//    copies of the per-block alpha window (C[i,k]=alpha[h,(i-k)&1023]).
//    pack_c kernel deleted. B-side: 4-deep global_load_lds pipeline with raw
//    "s_waitcnt vmcnt(4); s_barrier" (never drains to 0 mid-loop).
//  - gemm1/gemmf: 3-buffer depth-2 pipeline, same raw-barrier scheme.
//  - x2 kept bf16-only (slotX, old Cbf region, lives until final);
//    g stored bf16 (reuses Vt region). ~125MB HBM saved.
//
// ws layout (bytes):
//  [0, 25165824)          slotA : xn_bf16 -> z1_bf16
//  [25165824, 50331648)   Vt    : gemm1 out ; reused as gbf after circ
//  [50331648, 75497472)   slotX : x2_bf16 (circ out, read by gemmf1 + final)
//  [75497472, 76677120)   W2t
//  [76677120, 79036416)   Wft
// total 79,036,416 B (same as R1-R5)

typedef __attribute__((ext_vector_type(8))) short bf16x8;
typedef __attribute__((ext_vector_type(4))) float f32x4;
typedef __attribute__((ext_vector_type(4))) unsigned short us4;

__device__ __forceinline__ unsigned short f2bf(float f) {
  unsigned int u = __builtin_bit_cast(unsigned int, f);
  u += 0x7FFFu + ((u >> 16) & 1u);
  return (unsigned short)(u >> 16);
}
__device__ __forceinline__ float bf2f(unsigned short u) {
  return __builtin_bit_cast(float, (unsigned int)u << 16);
}

__device__ __forceinline__ void g2l16(const void* g, void* l) {
  __builtin_amdgcn_global_load_lds(
      (const __attribute__((address_space(1))) unsigned int*)g,
      (__attribute__((address_space(3))) unsigned int*)l,
      16, 0, 0);
}

// raw barrier: wait for all but n outstanding vmem, all lds ops, then barrier.
#define WAITB(n) asm volatile("s_waitcnt vmcnt(" #n ") lgkmcnt(0)\n\ts_barrier" ::: "memory")

// ---------------- pack kernels ----------------
__global__ __launch_bounds__(256) void pack_w2t(const float* __restrict__ Wv,
                                                unsigned short* __restrict__ W2t) {
  int o = blockIdx.x * 256 + threadIdx.x;
  int np = o / 768, d = o - np * 768;
  int h = np >> 6, k = np & 63;
  W2t[o] = f2bf(Wv[h * 49152 + d * 64 + k]);
}

__global__ __launch_bounds__(256) void pack_wft(const float* __restrict__ Wf,
                                                unsigned short* __restrict__ Wft) {
  int o = blockIdx.x * 256 + threadIdx.x;
  int l = o / 589824, rem = o - l * 589824;
  int np = rem / 768, d = rem - np * 768;
  Wft[o] = f2bf(Wf[l * 589824 + d * 768 + np]);
}

// ---------------- row kernels ----------------
__device__ __forceinline__ void wave_reduce2(float& s, float& s2) {
#pragma unroll
  for (int off = 32; off > 0; off >>= 1) {
    s += __shfl_down(s, off);
    s2 += __shfl_down(s2, off);
  }
  s = __shfl(s, 0);
  s2 = __shfl(s2, 0);
}

__global__ __launch_bounds__(256) void ln1_kernel(const float* __restrict__ x,
                                                  const float* __restrict__ sc,
                                                  const float* __restrict__ bi,
                                                  unsigned short* __restrict__ out) {
  int row = blockIdx.x * 4 + (threadIdx.x >> 6);
  int lane = threadIdx.x & 63;
  size_t base = (size_t)row * 768;
  float4 v[3];
#pragma unroll
  for (int j = 0; j < 3; ++j) v[j] = *(const float4*)(x + base + lane * 4 + j * 256);
  float s = 0.f, s2 = 0.f;
#pragma unroll
  for (int j = 0; j < 3; ++j) {
    s += v[j].x + v[j].y + v[j].z + v[j].w;
    s2 += v[j].x * v[j].x + v[j].y * v[j].y + v[j].z * v[j].z + v[j].w * v[j].w;
  }
  wave_reduce2(s, s2);
  float mu = s * (1.0f / 768.0f);
  float var = s2 * (1.0f / 768.0f) - mu * mu;
  float r = rsqrtf(var + 1e-6f);
#pragma unroll
  for (int j = 0; j < 3; ++j) {
    int d = lane * 4 + j * 256;
    float4 scv = *(const float4*)(sc + d);
    float4 biv = *(const float4*)(bi + d);
    us4 o;
    o[0] = f2bf((v[j].x - mu) * r * scv.x + biv.x);
    o[1] = f2bf((v[j].y - mu) * r * scv.y + biv.y);
    o[2] = f2bf((v[j].z - mu) * r * scv.z + biv.z);
    o[3] = f2bf((v[j].w - mu) * r * scv.w + biv.w);
    *(us4*)(out + base + d) = o;
  }
}

// g is bf16 now
__global__ __launch_bounds__(256) void lnswish_kernel(const unsigned short* __restrict__ g,
                                                      const float* __restrict__ sc,
                                                      const float* __restrict__ bi,
                                                      unsigned short* __restrict__ out) {
  int row = blockIdx.x * 4 + (threadIdx.x >> 6);
  int lane = threadIdx.x & 63;
  size_t base = (size_t)row * 768;
  float v[3][4];
#pragma unroll
  for (int j = 0; j < 3; ++j) {
    us4 gv = *(const us4*)(g + base + lane * 4 + j * 256);
#pragma unroll
    for (int q = 0; q < 4; ++q) v[j][q] = bf2f(gv[q]);
  }
  float s = 0.f, s2 = 0.f;
#pragma unroll
  for (int j = 0; j < 3; ++j)
#pragma unroll
    for (int q = 0; q < 4; ++q) { s += v[j][q]; s2 += v[j][q] * v[j][q]; }
  wave_reduce2(s, s2);
  float mu = s * (1.0f / 768.0f);
  float var = s2 * (1.0f / 768.0f) - mu * mu;
  float r = rsqrtf(var + 1e-6f);
#pragma unroll
  for (int j = 0; j < 3; ++j) {
    int d = lane * 4 + j * 256;
    float4 scv = *(const float4*)(sc + d);
    float4 biv = *(const float4*)(bi + d);
    const float* scp = &scv.x;
    const float* bip = &biv.x;
    us4 o;
#pragma unroll
    for (int q = 0; q < 4; ++q) {
      float z = (v[j][q] - mu) * r * scp[q] + bip[q];
      o[q] = f2bf(z / (1.0f + __expf(-z)));
    }
    *(us4*)(out + base + d) = o;
  }
}

// g bf16, x2 bf16 -> out f32
__global__ __launch_bounds__(256) void final_kernel(const unsigned short* __restrict__ g,
                                                    const float* __restrict__ sc,
                                                    const float* __restrict__ bi,
                                                    const unsigned short* __restrict__ x2,
                                                    float* __restrict__ out) {
  int row = blockIdx.x * 4 + (threadIdx.x >> 6);
  int lane = threadIdx.x & 63;
  size_t base = (size_t)row * 768;
  float v[3][4];
#pragma unroll
  for (int j = 0; j < 3; ++j) {
    us4 gv = *(const us4*)(g + base + lane * 4 + j * 256);
#pragma unroll
    for (int q = 0; q < 4; ++q) v[j][q] = bf2f(gv[q]);
  }
  float s = 0.f, s2 = 0.f;
#pragma unroll
  for (int j = 0; j < 3; ++j)
#pragma unroll
    for (int q = 0; q < 4; ++q) { s += v[j][q]; s2 += v[j][q] * v[j][q]; }
  wave_reduce2(s, s2);
  float mu = s * (1.0f / 768.0f);
  float var = s2 * (1.0f / 768.0f) - mu * mu;
  float r = rsqrtf(var + 1e-6f);
#pragma unroll
  for (int j = 0; j < 3; ++j) {
    int d = lane * 4 + j * 256;
    float4 scv = *(const float4*)(sc + d);
    float4 biv = *(const float4*)(bi + d);
    us4 xv = *(const us4*)(x2 + base + d);
    const float* scp = &scv.x;
    const float* bip = &biv.x;
    float4 o;
    float* op = &o.x;
#pragma unroll
    for (int q = 0; q < 4; ++q) {
      float z = (v[j][q] - mu) * r * scp[q] + bip[q];
      float sw = z / (1.0f + __expf(-z));
      float t = sw + bf2f(xv[q]);
      float ax = fabsf(t);
      op[q] = ax + __logf(1.0f + __expf(-2.0f * ax)) - 0.69314718055994531f;
    }
    *(float4*)(out + base + d) = o;
  }
}

// ---------- async GEMM core: 128x128, BK=32, 3-buffer depth-2 pipeline ----
__device__ __forceinline__ void gemm_core(const unsigned short* __restrict__ A,
                                          const unsigned short* __restrict__ Bt,
                                          int K, int m0, int n0,
                                          unsigned short* sA, unsigned short* sB,
                                          f32x4 acc[4][4]) {
  const int tid = threadIdx.x;
  const int wave = tid >> 6, lane = tid & 63;
  const int wm = (wave >> 1) << 6, wn = (wave & 1) << 6;
  const int fm = lane & 15, fq = lane >> 4;
  const int r0 = tid >> 2, r1 = r0 + 64;
  const int cg = tid & 3;
  const int cs0 = (cg ^ ((r0 >> 1) & 3)) << 3;
  const int cs1 = (cg ^ ((r1 >> 1) & 3)) << 3;
  const int ld0 = r0 * 32 + (cg << 3);
  const int ld1 = r1 * 32 + (cg << 3);
  const int niter = K >> 5;

#define STAGE(k0v, buf)                                                       \
  {                                                                           \
    unsigned short* dA = sA + (buf) * 4096;                                   \
    unsigned short* dB = sB + (buf) * 4096;                                   \
    g2l16(A + (size_t)(m0 + r0) * K + (k0v) + cs0, dA + ld0);                 \
    g2l16(Bt + (size_t)(n0 + r0) * K + (k0v) + cs0, dB + ld0);                \
    g2l16(A + (size_t)(m0 + r1) * K + (k0v) + cs1, dA + ld1);                 \
    g2l16(Bt + (size_t)(n0 + r1) * K + (k0v) + cs1, dB + ld1);                \
  }
#define GCOMP(bc)                                                             \
  {                                                                           \
    const unsigned short* pA = sA + (bc) * 4096;                              \
    const unsigned short* pB = sB + (bc) * 4096;                              \
    bf16x8 aq[4], bq[4];                                                      \
    _Pragma("unroll") for (int t = 0; t < 4; ++t) {                           \
      int ra = wm + (t << 4) + fm;                                            \
      int rb = wn + (t << 4) + fm;                                            \
      aq[t] = *(const bf16x8*)(pA + (ra << 5) + ((fq ^ ((ra >> 1) & 3)) << 3)); \
      bq[t] = *(const bf16x8*)(pB + (rb << 5) + ((fq ^ ((rb >> 1) & 3)) << 3)); \
    }                                                                         \
    _Pragma("unroll") for (int mt = 0; mt < 4; ++mt)                          \
    _Pragma("unroll") for (int nt = 0; nt < 4; ++nt)                          \
      acc[mt][nt] = __builtin_amdgcn_mfma_f32_16x16x32_bf16(aq[mt], bq[nt],   \
                                                            acc[mt][nt], 0, 0, 0); \
  }

  STAGE(0, 0);
  STAGE(32, 1);
  int bs = 2, bc = 0;
  for (int it = 0; it < niter - 1; ++it) {
    WAITB(4);                    // stage(it) landed; stage(it+1) in flight
    if (it + 2 < niter) {
      STAGE((it + 2) << 5, bs);
      bs = (bs == 2) ? 0 : bs + 1;
    }
    GCOMP(bc);
    bc = (bc == 2) ? 0 : bc + 1;
  }
  WAITB(0);
  GCOMP(bc);
#undef STAGE
}

__device__ __forceinline__ void decode_mn_768(int f, int& m0, int& n0) {
  int xcd = f & 7, s = f >> 3;
  int g = s / 6, bx = s - g * 6;
  m0 = (xcd + g * 8) << 7;
  n0 = bx << 7;
}

// GEMM1: xn @ W2t -> Vt[h][b*64+k][n] (bf16)
__global__ __launch_bounds__(256, 3) void gemm1_kernel(const unsigned short* __restrict__ A,
                                                       const unsigned short* __restrict__ Bt,
                                                       unsigned short* __restrict__ Vt) {
  __shared__ unsigned short sA[3 * 4096];
  __shared__ unsigned short sB[3 * 4096];
  f32x4 acc[4][4] = {};
  int m0, n0;
  decode_mn_768(blockIdx.x, m0, n0);
  gemm_core(A, Bt, 768, m0, n0, sA, sB, acc);
  const int wave = threadIdx.x >> 6, lane = threadIdx.x & 63;
  const int wm = (wave >> 1) << 6, wn = (wave & 1) << 6;
  const int fm = lane & 15, fq = lane >> 4;
#pragma unroll
  for (int mt = 0; mt < 4; ++mt) {
    int rowb = m0 + wm + (mt << 4) + (fq << 2);
    int b = rowb >> 10, n = rowb & 1023;
#pragma unroll
    for (int nt = 0; nt < 4; ++nt) {
      int col = n0 + wn + (nt << 4) + fm;
      int h = col >> 6, ck = col & 63;
      size_t off = ((size_t)h << 20) + (size_t)((b << 6) + ck) * 1024 + n;
      us4 v;
#pragma unroll
      for (int r = 0; r < 4; ++r) v[r] = f2bf(acc[mt][nt][r]);
      *(us4*)(Vt + off) = v;
    }
  }
}

// circGEMM: A from alpha (circulant, LDS-resident shifted copies), B = Vt_h
// epilogue: x2 = x + y, bf16 only.
__global__ __launch_bounds__(256, 3) void circ_kernel(const float* __restrict__ alpha,
                                                      const unsigned short* __restrict__ Vt,
                                                      const float* __restrict__ xin,
                                                      unsigned short* __restrict__ x2bf) {
  __shared__ unsigned short sAc[8 * 1168];   // 8 shift-copies of alpha window
  __shared__ unsigned short sB[4 * 4096];    // 4-deep B pipeline
  f32x4 acc[4][4] = {};
  int f = blockIdx.x;
  int xcd = f & 7, s = f >> 3;
  int h = s >> 3, t = s & 7;
  int mr = xcd >> 1, nr = xcd & 1;
  int m0 = ((mr << 1) + (t >> 2)) << 7;
  int n0 = ((nr << 2) + (t & 3)) << 7;

  const int tid = threadIdx.x;
  const int wave = tid >> 6, lane = tid & 63;
  const int wm = (wave >> 1) << 6, wn = (wave & 1) << 6;
  const int fm = lane & 15, fq = lane >> 4;

  // fill copies: sAc[c][u] = C-strip value at t = tmin+u+c, tmin = 897-m0
  // Arev[t] = alpha[h, (-t)&1023]  =>  index = (m0 - 897 - u - c) & 1023
  const float* ah = alpha + (h << 10);
#pragma unroll
  for (int c = 0; c < 8; ++c)
    for (int u = tid; u < 1160; u += 256)
      sAc[c * 1168 + u] = f2bf(ah[(m0 - 897 - u - c) & 1023]);
  asm volatile("s_waitcnt vmcnt(0)" ::: "memory");  // flush fill loads from vmcnt

  const unsigned short* Bt = Vt + ((size_t)h << 20);
  const int r0 = tid >> 2, r1 = r0 + 64;
  const int cg = tid & 3;
  const int cs0 = (cg ^ ((r0 >> 1) & 3)) << 3;
  const int cs1 = (cg ^ ((r1 >> 1) & 3)) << 3;
  const int ld0 = r0 * 32 + (cg << 3);
  const int ld1 = r1 * 32 + (cg << 3);

#define STAGEB(k0v, buf)                                                      \
  {                                                                           \
    unsigned short* dB = sB + (buf) * 4096;                                   \
    g2l16(Bt + (size_t)(n0 + r0) * 1024 + (k0v) + cs0, dB + ld0);             \
    g2l16(Bt + (size_t)(n0 + r1) * 1024 + (k0v) + cs1, dB + ld1);             \
  }
#define CCOMP(it)                                                             \
  {                                                                           \
    const unsigned short* pB = sB + ((it) & 3) * 4096;                        \
    int k0v = (it) << 5;                                                      \
    bf16x8 aq[4], bq[4];                                                      \
    _Pragma("unroll") for (int t_ = 0; t_ < 4; ++t_) {                        \
      int rl = wm + (t_ << 4) + fm;                                           \
      int d = k0v + (fq << 3) + 127 - rl;                                     \
      int c = d & 7;                                                          \
      aq[t_] = *(const bf16x8*)(sAc + c * 1168 + (d - c));                    \
      int rb = wn + (t_ << 4) + fm;                                           \
      bq[t_] = *(const bf16x8*)(pB + (rb << 5) + ((fq ^ ((rb >> 1) & 3)) << 3)); \
    }                                                                         \
    _Pragma("unroll") for (int mt = 0; mt < 4; ++mt)                          \
    _Pragma("unroll") for (int nt = 0; nt < 4; ++nt)                          \
      acc[mt][nt] = __builtin_amdgcn_mfma_f32_16x16x32_bf16(aq[mt], bq[nt],   \
                                                            acc[mt][nt], 0, 0, 0); \
  }

  STAGEB(0, 0);
  STAGEB(32, 1);
  STAGEB(64, 2);
  for (int it = 0; it < 30; ++it) {
    WAITB(4);                     // stage(it) landed; it+1, it+2 in flight
    if (it < 29) STAGEB((it + 3) << 5, (it + 3) & 3);
    CCOMP(it);
  }
  WAITB(2);
  CCOMP(30);
  WAITB(0);
  CCOMP(31);
#undef STAGEB

  // epilogue: x2 = x + y (bf16)
#pragma unroll
  for (int mt = 0; mt < 4; ++mt) {
    int ib = m0 + wm + (mt << 4) + (fq << 2);
#pragma unroll
    for (int nt = 0; nt < 4; ++nt) {
      int c = n0 + wn + (nt << 4) + fm;
      int b = c >> 6, k = c & 63;
      size_t off = ((size_t)(b << 10) + ib) * 768 + (h << 6) + k;
#pragma unroll
      for (int r = 0; r < 4; ++r) {
        float val = acc[mt][nt][r] + xin[off + (size_t)r * 768];
        x2bf[off + (size_t)r * 768] = f2bf(val);
      }
    }
  }
}

// FFN GEMM: A(bf16) @ Wt + bias -> g (bf16)
__global__ __launch_bounds__(256, 3) void gemmf_kernel(const unsigned short* __restrict__ A,
                                                       const unsigned short* __restrict__ Bt,
                                                       const float* __restrict__ bias,
                                                       unsigned short* __restrict__ g) {
  __shared__ unsigned short sA[3 * 4096];
  __shared__ unsigned short sB[3 * 4096];
  f32x4 acc[4][4] = {};
  int m0, n0;
  decode_mn_768(blockIdx.x, m0, n0);
  gemm_core(A, Bt, 768, m0, n0, sA, sB, acc);
  const int wave = threadIdx.x >> 6, lane = threadIdx.x & 63;
  const int wm = (wave >> 1) << 6, wn = (wave & 1) << 6;
  const int fm = lane & 15, fq = lane >> 4;
#pragma unroll
  for (int mt = 0; mt < 4; ++mt) {
    int rowb = m0 + wm + (mt << 4) + (fq << 2);
#pragma unroll
    for (int nt = 0; nt < 4; ++nt) {
      int col = n0 + wn + (nt << 4) + fm;
      float bc = bias[col];
#pragma unroll
      for (int r = 0; r < 4; ++r)
        g[(size_t)(rowb + r) * 768 + col] = f2bf(acc[mt][nt][r] + bc);
    }
  }
}

extern "C" void kernel_launch(void* const* d_in, const int* in_sizes, int n_in,
                              void* d_out, int out_size, void* d_ws, size_t ws_size,
                              hipStream_t stream) {
  const float* x = (const float*)d_in[0];
  const float* ln1_s = (const float*)d_in[1];
  const float* ln1_b = (const float*)d_in[2];
  const float* Wv = (const float*)d_in[3];
  const float* alpha = (const float*)d_in[4];
  const float* Wf = (const float*)d_in[5];
  const float* bf = (const float*)d_in[6];
  const float* lnf_s = (const float*)d_in[7];
  const float* lnf_b = (const float*)d_in[8];
  float* out = (float*)d_out;

  char* ws = (char*)d_ws;
  unsigned short* slotA = (unsigned short*)ws;                   // xn -> z1
  unsigned short* Vt = (unsigned short*)(ws + 25165824);         // Vt -> gbf
  unsigned short* gbf = Vt;
  unsigned short* slotX = (unsigned short*)(ws + 50331648);      // x2 bf16
  unsigned short* W2t = (unsigned short*)(ws + 75497472);
  unsigned short* Wft = (unsigned short*)(ws + 76677120);

  pack_w2t<<<2304, 256, 0, stream>>>(Wv, W2t);
  pack_wft<<<4608, 256, 0, stream>>>(Wf, Wft);

  ln1_kernel<<<4096, 256, 0, stream>>>(x, ln1_s, ln1_b, slotA);
  gemm1_kernel<<<768, 256, 0, stream>>>(slotA, W2t, Vt);
  circ_kernel<<<768, 256, 0, stream>>>(alpha, Vt, x, slotX);
  gemmf_kernel<<<768, 256, 0, stream>>>(slotX, Wft, bf, gbf);
  lnswish_kernel<<<4096, 256, 0, stream>>>(gbf, lnf_s, lnf_b, slotA);
  gemmf_kernel<<<768, 256, 0, stream>>>(slotA, Wft + 589824, bf + 768, gbf);
  final_kernel<<<4096, 256, 0, stream>>>(gbf, lnf_s + 768, lnf_b + 768, slotX, out);
}